// Round 10
// baseline (1054.071 us; speedup 1.0000x reference)
//
#include <hip/hip_runtime.h>

typedef unsigned short u16;
typedef unsigned int u32;
typedef short s8v __attribute__((ext_vector_type(8)));
typedef float f4 __attribute__((ext_vector_type(4)));

#define GL16(g, l) __builtin_amdgcn_global_load_lds((const __attribute__((address_space(1))) u32*)(g), (__attribute__((address_space(3))) u32*)(l), 16, 0, 0)

__device__ __forceinline__ u16 f2bf(float f){
  u32 u = __builtin_bit_cast(u32, f);
  u32 r = u + 0x7fffu + ((u >> 16) & 1u);
  return (u16)(r >> 16);
}
__device__ __forceinline__ float bf2f(u16 u){
  u32 x = ((u32)u) << 16;
  return __builtin_bit_cast(float, x);
}

// pack 2 f32 -> 2 bf16 (RNE), one instruction
__device__ __forceinline__ u32 pk_bf16(float lo, float hi){
  u32 r;
  asm("v_cvt_pk_bf16_f32 %0, %1, %2" : "=v"(r) : "v"(lo), "v"(hi));
  return r;
}

// exact-grade gelu: erf via Abramowitz-Stegun 7.1.26 (|eps|<=1.5e-7)
__device__ __forceinline__ float gelu_f(float x){
  float y = fabsf(x) * 0.70710678118654752f;
  float t = __builtin_amdgcn_rcpf(1.f + 0.3275911f*y);
  float p = ((((1.061405429f*t - 1.453152027f)*t + 1.421413741f)*t - 0.284496736f)*t + 0.254829592f)*t;
  float er = 1.f - p*__expf(-y*y);
  er = copysignf(er, x);
  return 0.5f*x*(1.f + er);
}

// window-order row (wi*49+n) -> natural token row (b*3136 + h*56 + w), shift=+3
__device__ __forceinline__ int win_to_src(int orow){
  int wi = orow / 49;
  int n  = orow - wi*49;
  int b  = wi >> 6;
  int wq = wi & 63;
  int wh = wq >> 3, ww = wq & 7;
  int r = n / 7, c = n - r*7;
  int hh = wh*7 + r + 3; if (hh >= 56) hh -= 56;
  int wp = ww*7 + c + 3; if (wp >= 56) wp -= 56;
  return (b*56 + hh)*56 + wp;
}

__global__ void sentinel_kernel(float* o){ o[0] = 1.0e9f; }

// (K,N) f32 -> (N,K) bf16; rows n < scale_lim get *scale (q-scale folding)
__global__ void transpose_cast(const float* __restrict__ in, u16* __restrict__ out,
                               int K, int N, float scale, int scale_lim){
  __shared__ float tile[16][17];
  int kb = blockIdx.x*16, nb = blockIdx.y*16;
  int tx = threadIdx.x, ty = threadIdx.y;
  int k = kb + ty, n = nb + tx;
  tile[ty][tx] = (k < K && n < N) ? in[(size_t)k*N + n] : 0.f;
  __syncthreads();
  int on = nb + ty, ok = kb + tx;
  if (on < N && ok < K){
    float v = tile[tx][ty];
    if (on < scale_lim) v *= scale;
    out[(size_t)on*K + ok] = f2bf(v);
  }
}

// prescale first `lim` entries of bias by s
__global__ void scale_bias(const float* __restrict__ in, float* __restrict__ out,
                           int n, float s, int lim){
  int i = blockIdx.x*256 + threadIdx.x;
  if (i < n) out[i] = in[i] * (i < lim ? s : 1.f);
}

// biasmask[wq][h][m][n], 64x12x64x64 BF16. m=query, n=key. -1e9 on pads.
__global__ void build_biasmask(const float* __restrict__ table, u16* __restrict__ bm){
  int wq = blockIdx.x, h = blockIdx.y;
  int wh = wq >> 3, ww = wq & 7;
  u16* o = bm + (size_t)(wq*12 + h) * 4096;
  for (int i = threadIdx.x; i < 4096; i += 256){
    int m = i >> 6, n = i & 63;
    float v;
    if (m < 49 && n < 49){
      int rm = m/7, cm = m - rm*7;
      int rn = n/7, cn = n - rn*7;
      int idx = (rm - rn + 6)*13 + (cm - cn + 6);
      v = table[idx*12 + h];
      int ym = wh*7 + rm, xm = ww*7 + cm;
      int yn = wh*7 + rn, xn = ww*7 + cn;
      int lm = (ym < 49 ? 0 : (ym < 53 ? 1 : 2))*3 + (xm < 49 ? 0 : (xm < 53 ? 1 : 2));
      int ln = (yn < 49 ? 0 : (yn < 53 ? 1 : 2))*3 + (xn < 49 ? 0 : (xn < 53 ? 1 : 2));
      if (lm != ln) v += -100.f;
    } else {
      v = -1e9f;
    }
    o[i] = f2bf(v);
  }
}

// LayerNorm over C=384, one wave per row. GATHER: row gathered via win_to_src.
template<bool GATHER>
__global__ __launch_bounds__(256) void ln_kernel(const float* __restrict__ x,
    const float* __restrict__ g, const float* __restrict__ b,
    u16* __restrict__ y, int nrows)
{
  int row = blockIdx.x*4 + (threadIdx.x >> 6);
  int lane = threadIdx.x & 63;
  if (row >= nrows) return;
  int src = GATHER ? win_to_src(row) : row;
  const float* xr = x + (size_t)src*384;
  float v[6];
  float s = 0.f, s2 = 0.f;
  #pragma unroll
  for (int p = 0; p < 3; p++){
    float2 t = *(const float2*)(xr + p*128 + lane*2);
    v[p*2] = t.x; v[p*2+1] = t.y;
    s += t.x + t.y; s2 += t.x*t.x + t.y*t.y;
  }
  #pragma unroll
  for (int off = 32; off; off >>= 1){
    s  += __shfl_xor(s,  off);
    s2 += __shfl_xor(s2, off);
  }
  float mean = s * (1.f/384.f);
  float var  = s2 * (1.f/384.f) - mean*mean;
  float rs   = rsqrtf(var + 1e-5f);
  u16* yr = y + (size_t)row*384;
  #pragma unroll
  for (int p = 0; p < 3; p++){
    int c = p*128 + lane*2;
    float a0 = (v[p*2]   - mean)*rs*g[c]   + b[c];
    float a1 = (v[p*2+1] - mean)*rs*g[c+1] + b[c+1];
    *(u32*)(yr + c) = pk_bf16(a0, a1);
  }
}

// ===========================================================================
// 128x128 GEMM, BK=32 (occupancy lever): LDS 32 KB -> 4-5 blocks/CU
// (~16 waves/CU vs r6's 8), same 64x64 wave tile (8 ds_read : 16 MFMA per
// step -- the ratio that worked), dbuf + counted vmcnt(4) + raw barriers
// (r5-verified), T2 chunk-XOR swizzle re-derived for 4-chunk rows (2-bit
// key; per-16-lane phase = 2-way = free), bijective XCD swizzle, bn-fastest,
// operand-swapped MFMA epilogue (lane = 4 consecutive n at fixed m).
// MODE 0: +bias, bf16 (QKV) | 1: +bias+resid scatter f32 (proj)
//      2: +bias+gelu bf16 (fc1) | 3: +bias accumulate f32 (fc2)
// ===========================================================================
template<int MODE, int NF>
__global__ __launch_bounds__(256) void gemm_bf16(
    const u16* __restrict__ A, const u16* __restrict__ Bt,
    const float* __restrict__ bias, const float* __restrict__ resid,
    void* __restrict__ outp, int K, int N, int gn)
{
  constexpr int TN = NF * 32;                 // 128
  __shared__ u16 As[2][128*32];
  __shared__ u16 Bs[2][TN*32];
  const int tid  = threadIdx.x;
  const int lane = tid & 63, wv = tid >> 6;
  const int wr = wv >> 1, wc = wv & 1;
  const int l15 = lane & 15, lhi = lane >> 4;
  const int sw2 = l15 & 3;                    // read-side swizzle key (row&3)

  int total = gridDim.x;
  int flat  = blockIdx.x;
  int swz   = flat;
  if ((total & 7) == 0){
    int cpx = total >> 3;
    swz = (flat & 7)*cpx + (flat >> 3);
  }
  int bm = swz / gn, bn = swz - bm*gn;
  const size_t m0 = (size_t)bm * 128;
  const int n0 = bn * TN;

  f4 acc[4][NF] = {};

  // stage one BK=32 K-tile (2 A + 2 B GL16 per thread)
  auto stage = [&](int buf, int kt){
    #pragma unroll
    for (int it = 0; it < 2; it++){
      int c = it*256 + tid;
      int row = c >> 2;
      int col = ((c & 3) ^ (row & 3)) * 8;    // inverse-swizzled source
      const u16* ga = A + (m0 + (size_t)row)*K + kt*32 + col;
      GL16(ga, &As[buf][(it*256 + wv*64)*8]);
    }
    #pragma unroll
    for (int it = 0; it < 2; it++){
      int c = it*256 + tid;
      int row = c >> 2;
      int col = ((c & 3) ^ (row & 3)) * 8;
      const u16* gb = Bt + ((size_t)n0 + row)*K + kt*32 + col;
      GL16(gb, &Bs[buf][(it*256 + wv*64)*8]);
    }
  };

  const int nk = K >> 5;
  stage(0, 0);
  for (int kt = 0; kt < nk; kt++){
    const int cur = kt & 1;
    if (kt + 1 < nk){
      stage(cur ^ 1, kt + 1);
      asm volatile("s_waitcnt vmcnt(4)" ::: "memory");   // own cur loads landed
    } else {
      asm volatile("s_waitcnt vmcnt(0)" ::: "memory");
    }
    __builtin_amdgcn_s_barrier();
    s8v a[4], bb[NF];
    #pragma unroll
    for (int mi = 0; mi < 4; mi++)
      a[mi] = *(const s8v*)&As[cur][(wr*64 + mi*16 + l15)*32 + (lhi ^ sw2)*8];
    #pragma unroll
    for (int ni = 0; ni < NF; ni++)
      bb[ni] = *(const s8v*)&Bs[cur][(wc*NF*16 + ni*16 + l15)*32 + (lhi ^ sw2)*8];
    #pragma unroll
    for (int mi = 0; mi < 4; mi++)
      #pragma unroll
      for (int ni = 0; ni < NF; ni++)
        acc[mi][ni] = __builtin_amdgcn_mfma_f32_16x16x32_bf16(bb[ni], a[mi], acc[mi][ni], 0, 0, 0);
    asm volatile("s_waitcnt lgkmcnt(0)" ::: "memory");
    __builtin_amdgcn_s_barrier();
  }

  // epilogue: lane holds 4 consecutive n at fixed m
  #pragma unroll
  for (int mi = 0; mi < 4; mi++){
    int m = (int)m0 + wr*64 + mi*16 + l15;
    int src = 0;
    if constexpr (MODE == 1) src = win_to_src(m);
    #pragma unroll
    for (int ni = 0; ni < NF; ni++){
      int n = n0 + wc*NF*16 + ni*16 + lhi*4;
      f4 v = acc[mi][ni];
      float4 b4 = *(const float4*)(bias + n);
      v[0] += b4.x; v[1] += b4.y; v[2] += b4.z; v[3] += b4.w;
      if constexpr (MODE == 0){
        uint2 pk; pk.x = pk_bf16(v[0], v[1]); pk.y = pk_bf16(v[2], v[3]);
        *(uint2*)((u16*)outp + (size_t)m*N + n) = pk;
      } else if constexpr (MODE == 1){
        const float4 r4 = *(const float4*)(resid + (size_t)src*384 + n);
        float4 o4; o4.x = v[0]+r4.x; o4.y = v[1]+r4.y; o4.z = v[2]+r4.z; o4.w = v[3]+r4.w;
        *(float4*)((float*)outp + (size_t)src*384 + n) = o4;
      } else if constexpr (MODE == 2){
        uint2 pk;
        pk.x = pk_bf16(gelu_f(v[0]), gelu_f(v[1]));
        pk.y = pk_bf16(gelu_f(v[2]), gelu_f(v[3]));
        *(uint2*)((u16*)outp + (size_t)m*N + n) = pk;
      } else {
        float4* o = (float4*)((float*)outp + (size_t)m*N + n);
        float4 c4 = *o;
        c4.x += v[0]; c4.y += v[1]; c4.z += v[2]; c4.w += v[3];
        *o = c4;
      }
    }
  }
}

// one wave per (window, head): S=QK^T (pad 49->64), +bias+mask, softmax, O=PV
// bm is bf16 (halves bias-read bytes); V loaded via b128.
__global__ __launch_bounds__(256) void attn_kernel(
    const u16* __restrict__ qkv, const u16* __restrict__ bm, u16* __restrict__ ao)
{
  const int wi = blockIdx.x;            // 0..2047
  const int hg = blockIdx.y;            // 0..2
  const int wv = threadIdx.x >> 6, lane = threadIdx.x & 63;
  const int h = hg*4 + wv;
  const int l15 = lane & 15, lhi = lane >> 4;
  const int wq = wi & 63;

  __shared__ u16 Plds[4][64*72];
  __shared__ u16 Vlds[4][32*72];

  const size_t base = (size_t)wi * 49 * 1152;
  s8v z8 = (s8v)0;

  // V -> LDS transposed: Vlds[d][n]; b128 global loads (4/lane)
  #pragma unroll
  for (int i = 0; i < 4; i++){
    int n  = i*16 + (lane >> 2);
    int d8 = (lane & 3)*8;
    s8v v = (n < 49) ? *(const s8v*)&qkv[base + (size_t)n*1152 + 768 + h*32 + d8] : z8;
    #pragma unroll
    for (int j = 0; j < 8; j++)
      Vlds[wv][(d8 + j)*72 + n] = (u16)v[j];
  }

  // Q,K fragments (hd=32 == one MFMA K-step)
  s8v aQ[4], bK[4];
  #pragma unroll
  for (int mi = 0; mi < 4; mi++){
    int rowq = mi*16 + l15;
    aQ[mi] = (rowq < 49) ? *(const s8v*)&qkv[base + (size_t)rowq*1152 +   0 + h*32 + lhi*8] : z8;
    bK[mi] = (rowq < 49) ? *(const s8v*)&qkv[base + (size_t)rowq*1152 + 384 + h*32 + lhi*8] : z8;
  }
  f4 zf = {0.f, 0.f, 0.f, 0.f};
  f4 s[4][4];
  #pragma unroll
  for (int mi = 0; mi < 4; mi++)
    #pragma unroll
    for (int ni = 0; ni < 4; ni++)
      s[mi][ni] = __builtin_amdgcn_mfma_f32_16x16x32_bf16(aQ[mi], bK[ni], zf, 0, 0, 0);

  // + rel-pos bias + shift mask (precomputed bf16, pads = -1e9)
  const u16* bmp = bm + (size_t)(wq*12 + h) * 4096;
  #pragma unroll
  for (int mi = 0; mi < 4; mi++)
    #pragma unroll
    for (int ni = 0; ni < 4; ni++)
      #pragma unroll
      for (int r = 0; r < 4; r++){
        int m = mi*16 + lhi*4 + r, n = ni*16 + l15;
        s[mi][ni][r] += bf2f(bmp[m*64 + n]);
      }

  // softmax over n: 4 in-register + 16-lane shfl_xor reduce
  #pragma unroll
  for (int mi = 0; mi < 4; mi++){
    #pragma unroll
    for (int r = 0; r < 4; r++){
      float mx = fmaxf(fmaxf(s[mi][0][r], s[mi][1][r]), fmaxf(s[mi][2][r], s[mi][3][r]));
      mx = fmaxf(mx, __shfl_xor(mx, 1));
      mx = fmaxf(mx, __shfl_xor(mx, 2));
      mx = fmaxf(mx, __shfl_xor(mx, 4));
      mx = fmaxf(mx, __shfl_xor(mx, 8));
      float sum = 0.f;
      #pragma unroll
      for (int ni = 0; ni < 4; ni++){
        float p = __expf(s[mi][ni][r] - mx);
        s[mi][ni][r] = p; sum += p;
      }
      sum += __shfl_xor(sum, 1);
      sum += __shfl_xor(sum, 2);
      sum += __shfl_xor(sum, 4);
      sum += __shfl_xor(sum, 8);
      float inv = 1.f / sum;
      #pragma unroll
      for (int ni = 0; ni < 4; ni++) s[mi][ni][r] *= inv;
    }
  }

  // P -> LDS (C-layout scatter, bf16)
  #pragma unroll
  for (int mi = 0; mi < 4; mi++)
    #pragma unroll
    for (int ni = 0; ni < 4; ni++)
      #pragma unroll
      for (int r = 0; r < 4; r++){
        int m = mi*16 + lhi*4 + r, n = ni*16 + l15;
        Plds[wv][m*72 + n] = f2bf(s[mi][ni][r]);
      }
  __syncthreads();

  // O = P @ V  (K=64 -> 2 k-steps)
  f4 o[4][2] = {};
  #pragma unroll
  for (int ks = 0; ks < 2; ks++){
    s8v aP[4], bV[2];
    #pragma unroll
    for (int mi = 0; mi < 4; mi++)
      aP[mi] = *(const s8v*)&Plds[wv][(mi*16 + l15)*72 + ks*32 + lhi*8];
    #pragma unroll
    for (int di = 0; di < 2; di++)
      bV[di] = *(const s8v*)&Vlds[wv][(di*16 + l15)*72 + ks*32 + lhi*8];
    #pragma unroll
    for (int mi = 0; mi < 4; mi++)
      #pragma unroll
      for (int di = 0; di < 2; di++)
        o[mi][di] = __builtin_amdgcn_mfma_f32_16x16x32_bf16(aP[mi], bV[di], o[mi][di], 0, 0, 0);
  }

  // store O rows < 49
  #pragma unroll
  for (int mi = 0; mi < 4; mi++)
    #pragma unroll
    for (int di = 0; di < 2; di++)
      #pragma unroll
      for (int r = 0; r < 4; r++){
        int m = mi*16 + lhi*4 + r;
        if (m < 49){
          int d = di*16 + l15;
          ao[((size_t)wi*49 + m)*384 + h*32 + d] = f2bf(o[mi][di][r]);
        }
      }
}

extern "C" void kernel_launch(void* const* d_in, const int* in_sizes, int n_in,
                              void* d_out, int out_size, void* d_ws, size_t ws_size,
                              hipStream_t stream)
{
  const float* x      = (const float*)d_in[0];
  const float* table  = (const float*)d_in[1];
  const float* qkv_w  = (const float*)d_in[2];
  const float* qkv_b  = (const float*)d_in[3];
  const float* proj_w = (const float*)d_in[4];
  const float* proj_b = (const float*)d_in[5];
  const float* n1w    = (const float*)d_in[6];
  const float* n1b    = (const float*)d_in[7];
  const float* n2w    = (const float*)d_in[8];
  const float* n2b    = (const float*)d_in[9];
  const float* w1     = (const float*)d_in[10];
  const float* b1     = (const float*)d_in[11];
  const float* w2     = (const float*)d_in[12];
  const float* b2     = (const float*)d_in[13];
  float* out = (float*)d_out;

  const size_t M = 100352;  // 32 * 3136 tokens (= 2048 windows * 49)
  const float SC = 0.17677669529663689f;  // hd^-0.5

  const size_t R1 = M * 1536 * 2;              // qkv (uses 1152 cols) | mlp hidden
  const size_t R2 = M * 384 * 2;               // ybf | ao | y2
  const size_t R3 = (size_t)64*12*64*64*2;     // biasmask (bf16)
  const size_t WT = (size_t)(1152*384 + 384*384 + 1536*384 + 384*1536) * 2;
  const size_t BB = 1152 * 4;                  // prescaled qkv bias
  const size_t needed = R1 + R2 + R3 + WT + BB;
  if (ws_size < needed){
    sentinel_kernel<<<1, 1, 0, stream>>>(out);
    return;
  }

  char* p = (char*)d_ws;
  u16*   qkvbuf = (u16*)p;                       // R1 (also mlp hidden)
  u16*   ybuf   = (u16*)(p + R1);                // R2 (ybf -> ao -> y2)
  u16*   bmbuf  = (u16*)(p + R1 + R2);           // R3
  u16*   qkvT   = (u16*)(p + R1 + R2 + R3);
  u16*   projT  = qkvT  + (size_t)1152*384;
  u16*   w1T    = projT + (size_t)384*384;
  u16*   w2T    = w1T   + (size_t)1536*384;
  float* qkvb_s = (float*)(p + R1 + R2 + R3 + WT);

  // weight transposes (K,N)->(N,K) bf16; q-scale folded into qkv rows < 384
  transpose_cast<<<dim3(24, 72),  dim3(16,16), 0, stream>>>(qkv_w,  qkvT, 384, 1152, SC, 384);
  transpose_cast<<<dim3(24, 24),  dim3(16,16), 0, stream>>>(proj_w, projT, 384, 384, 1.f, 0);
  transpose_cast<<<dim3(24, 96),  dim3(16,16), 0, stream>>>(w1,     w1T,  384, 1536, 1.f, 0);
  transpose_cast<<<dim3(96, 24),  dim3(16,16), 0, stream>>>(w2,     w2T,  1536, 384, 1.f, 0);
  scale_bias<<<5, 256, 0, stream>>>(qkv_b, qkvb_s, 1152, SC, 384);
  build_biasmask<<<dim3(64, 12), 256, 0, stream>>>(table, bmbuf);

  // LN1 with shift+window gather -> ybf (window-ordered rows)
  ln_kernel<true><<<M/4, 256, 0, stream>>>(x, n1w, n1b, ybuf, (int)M);

  // QKV GEMM: ybf @ qkv_w + b (q prescaled), bf16 out. 128-tile BK=32, gn=9
  gemm_bf16<0,4><<<784*9, 256, 0, stream>>>(ybuf, qkvT, qkvb_s, nullptr, qkvbuf, 384, 1152, 9);

  // windowed attention -> ao (overwrites ybf)
  attn_kernel<<<dim3(2048, 3), 256, 0, stream>>>(qkvbuf, bmbuf, ybuf);

  // proj GEMM + un-shift scatter + residual -> out (= x2). gn=3
  gemm_bf16<1,4><<<784*3, 256, 0, stream>>>(ybuf, projT, proj_b, x, out, 384, 384, 3);

  // LN2 -> y2 (reuses ybuf)
  ln_kernel<false><<<M/4, 256, 0, stream>>>(out, n2w, n2b, ybuf, (int)M);

  // MLP fc1 + gelu -> hidden (reuses qkvbuf region). gn=12
  gemm_bf16<2,4><<<784*12, 256, 0, stream>>>(ybuf, w1T, b1, nullptr, qkvbuf, 384, 1536, 12);

  // MLP fc2, accumulate into out (x2 + mlp). gn=3
  gemm_bf16<3,4><<<784*3, 256, 0, stream>>>(qkvbuf, w2T, b2, nullptr, out, 1536, 384, 3);
}

// Round 11
// 969.521 us; speedup vs baseline: 1.0872x; 1.0872x over previous
//
#include <hip/hip_runtime.h>

typedef unsigned short u16;
typedef unsigned int u32;
typedef short s8v __attribute__((ext_vector_type(8)));
typedef float f4 __attribute__((ext_vector_type(4)));

#define GL16(g, l) __builtin_amdgcn_global_load_lds((const __attribute__((address_space(1))) u32*)(g), (__attribute__((address_space(3))) u32*)(l), 16, 0, 0)

__device__ __forceinline__ u16 f2bf(float f){
  u32 u = __builtin_bit_cast(u32, f);
  u32 r = u + 0x7fffu + ((u >> 16) & 1u);
  return (u16)(r >> 16);
}
__device__ __forceinline__ float bf2f(u16 u){
  u32 x = ((u32)u) << 16;
  return __builtin_bit_cast(float, x);
}

// pack 2 f32 -> 2 bf16 (RNE), one instruction
__device__ __forceinline__ u32 pk_bf16(float lo, float hi){
  u32 r;
  asm("v_cvt_pk_bf16_f32 %0, %1, %2" : "=v"(r) : "v"(lo), "v"(hi));
  return r;
}

// exact-grade gelu: erf via Abramowitz-Stegun 7.1.26 (|eps|<=1.5e-7)
__device__ __forceinline__ float gelu_f(float x){
  float y = fabsf(x) * 0.70710678118654752f;
  float t = __builtin_amdgcn_rcpf(1.f + 0.3275911f*y);
  float p = ((((1.061405429f*t - 1.453152027f)*t + 1.421413741f)*t - 0.284496736f)*t + 0.254829592f)*t;
  float er = 1.f - p*__expf(-y*y);
  er = copysignf(er, x);
  return 0.5f*x*(1.f + er);
}

// window-order row (wi*49+n) -> natural token row (b*3136 + h*56 + w), shift=+3
__device__ __forceinline__ int win_to_src(int orow){
  int wi = orow / 49;
  int n  = orow - wi*49;
  int b  = wi >> 6;
  int wq = wi & 63;
  int wh = wq >> 3, ww = wq & 7;
  int r = n / 7, c = n - r*7;
  int hh = wh*7 + r + 3; if (hh >= 56) hh -= 56;
  int wp = ww*7 + c + 3; if (wp >= 56) wp -= 56;
  return (b*56 + hh)*56 + wp;
}

__global__ void sentinel_kernel(float* o){ o[0] = 1.0e9f; }

// (K,N) f32 -> (N,K) bf16; rows n < scale_lim get *scale (q-scale folding)
__global__ void transpose_cast(const float* __restrict__ in, u16* __restrict__ out,
                               int K, int N, float scale, int scale_lim){
  __shared__ float tile[16][17];
  int kb = blockIdx.x*16, nb = blockIdx.y*16;
  int tx = threadIdx.x, ty = threadIdx.y;
  int k = kb + ty, n = nb + tx;
  tile[ty][tx] = (k < K && n < N) ? in[(size_t)k*N + n] : 0.f;
  __syncthreads();
  int on = nb + ty, ok = kb + tx;
  if (on < N && ok < K){
    float v = tile[tx][ty];
    if (on < scale_lim) v *= scale;
    out[(size_t)on*K + ok] = f2bf(v);
  }
}

// prescale first `lim` entries of bias by s
__global__ void scale_bias(const float* __restrict__ in, float* __restrict__ out,
                           int n, float s, int lim){
  int i = blockIdx.x*256 + threadIdx.x;
  if (i < n) out[i] = in[i] * (i < lim ? s : 1.f);
}

// biasmask[wq][h][m][n], 64x12x64x64 BF16. m=query, n=key. -1e9 on pads.
__global__ void build_biasmask(const float* __restrict__ table, u16* __restrict__ bm){
  int wq = blockIdx.x, h = blockIdx.y;
  int wh = wq >> 3, ww = wq & 7;
  u16* o = bm + (size_t)(wq*12 + h) * 4096;
  for (int i = threadIdx.x; i < 4096; i += 256){
    int m = i >> 6, n = i & 63;
    float v;
    if (m < 49 && n < 49){
      int rm = m/7, cm = m - rm*7;
      int rn = n/7, cn = n - rn*7;
      int idx = (rm - rn + 6)*13 + (cm - cn + 6);
      v = table[idx*12 + h];
      int ym = wh*7 + rm, xm = ww*7 + cm;
      int yn = wh*7 + rn, xn = ww*7 + cn;
      int lm = (ym < 49 ? 0 : (ym < 53 ? 1 : 2))*3 + (xm < 49 ? 0 : (xm < 53 ? 1 : 2));
      int ln = (yn < 49 ? 0 : (yn < 53 ? 1 : 2))*3 + (xn < 49 ? 0 : (xn < 53 ? 1 : 2));
      if (lm != ln) v += -100.f;
    } else {
      v = -1e9f;
    }
    o[i] = f2bf(v);
  }
}

// LayerNorm over C=384, one wave per row. GATHER: row gathered via win_to_src.
template<bool GATHER>
__global__ __launch_bounds__(256) void ln_kernel(const float* __restrict__ x,
    const float* __restrict__ g, const float* __restrict__ b,
    u16* __restrict__ y, int nrows)
{
  int row = blockIdx.x*4 + (threadIdx.x >> 6);
  int lane = threadIdx.x & 63;
  if (row >= nrows) return;
  int src = GATHER ? win_to_src(row) : row;
  const float* xr = x + (size_t)src*384;
  float v[6];
  float s = 0.f, s2 = 0.f;
  #pragma unroll
  for (int p = 0; p < 3; p++){
    float2 t = *(const float2*)(xr + p*128 + lane*2);
    v[p*2] = t.x; v[p*2+1] = t.y;
    s += t.x + t.y; s2 += t.x*t.x + t.y*t.y;
  }
  #pragma unroll
  for (int off = 32; off; off >>= 1){
    s  += __shfl_xor(s,  off);
    s2 += __shfl_xor(s2, off);
  }
  float mean = s * (1.f/384.f);
  float var  = s2 * (1.f/384.f) - mean*mean;
  float rs   = rsqrtf(var + 1e-5f);
  u16* yr = y + (size_t)row*384;
  #pragma unroll
  for (int p = 0; p < 3; p++){
    int c = p*128 + lane*2;
    float a0 = (v[p*2]   - mean)*rs*g[c]   + b[c];
    float a1 = (v[p*2+1] - mean)*rs*g[c+1] + b[c+1];
    *(u32*)(yr + c) = pk_bf16(a0, a1);
  }
}

// ===========================================================================
// 128x128 GEMM, BK=64 (r6-verified config: dbuf, counted vmcnt(8), raw
// barriers, T2 8-chunk XOR swizzle -> conflicts=0, bijective XCD swizzle,
// bn-fastest, operand-swapped MFMA).
// NEW (r11): bf16 MODES (0,2) write through an LDS-transpose epilogue:
// acc -> bf16 LDS tile (128 x stride-136), barrier, then each thread streams
// 8 x uint4 (16B) with 16 FULL 256B-contiguous rows per store instruction
// (full 64B sectors), replacing the 8B/lane 32B-row-chunk patter.
// f32 MODES (1,3) already store float4/lane (full sectors) - unchanged.
// MODE 0: +bias, bf16 (QKV) | 1: +bias+resid scatter f32 (proj)
//      2: +bias+gelu bf16 (fc1) | 3: +bias accumulate f32 (fc2)
// ===========================================================================
template<int MODE, int NF>
__global__ __launch_bounds__(256) void gemm_bf16(
    const u16* __restrict__ A, const u16* __restrict__ Bt,
    const float* __restrict__ bias, const float* __restrict__ resid,
    void* __restrict__ outp, int K, int N, int gn)
{
  constexpr int TN = NF * 32;   // 128
  __shared__ u16 As[2][128*64];
  __shared__ u16 Bs[2][TN*64];
  const int tid  = threadIdx.x;
  const int lane = tid & 63, wv = tid >> 6;
  const int wr = wv >> 1, wc = wv & 1;
  const int l15 = lane & 15, lhi = lane >> 4;
  const int sw  = l15 & 7;              // read-side swizzle key (row&7 == l15&7)

  int total = gridDim.x;
  int flat  = blockIdx.x;
  int swz   = flat;
  if ((total & 7) == 0){
    int cpx = total >> 3;
    swz = (flat & 7)*cpx + (flat >> 3);
  }
  int bm = swz / gn, bn = swz - bm*gn;
  const size_t m0 = (size_t)bm * 128;
  const int n0 = bn * TN;

  f4 acc[4][NF] = {};

  // stage one K-tile (4+NF = 8 GL16 per thread) into buffer `buf`
  auto stage = [&](int buf, int kt){
    #pragma unroll
    for (int it = 0; it < 4; it++){
      int c = it*256 + tid;
      int row = c >> 3;
      int col = (((c & 7) ^ (row & 7))) * 8;   // inverse-swizzled source
      const u16* ga = A + (m0 + (size_t)row)*K + kt*64 + col;
      GL16(ga, &As[buf][(it*256 + wv*64)*8]);
    }
    #pragma unroll
    for (int it = 0; it < NF; it++){
      int c = it*256 + tid;
      int row = c >> 3;
      int col = (((c & 7) ^ (row & 7))) * 8;
      const u16* gb = Bt + ((size_t)n0 + row)*K + kt*64 + col;
      GL16(gb, &Bs[buf][(it*256 + wv*64)*8]);
    }
  };

  const int nk = K >> 6;
  stage(0, 0);
  for (int kt = 0; kt < nk; kt++){
    const int cur = kt & 1;
    if (kt + 1 < nk){
      stage(cur ^ 1, kt + 1);
      asm volatile("s_waitcnt vmcnt(8)" ::: "memory");   // own cur loads landed
    } else {
      asm volatile("s_waitcnt vmcnt(0)" ::: "memory");
    }
    __builtin_amdgcn_s_barrier();                         // everyone's landed
    #pragma unroll
    for (int kk = 0; kk < 2; kk++){
      s8v a[4], bb[NF];
      #pragma unroll
      for (int mi = 0; mi < 4; mi++)
        a[mi] = *(const s8v*)&As[cur][(wr*64 + mi*16 + l15)*64 + ((kk*4 + lhi) ^ sw)*8];
      #pragma unroll
      for (int ni = 0; ni < NF; ni++)
        bb[ni] = *(const s8v*)&Bs[cur][(wc*NF*16 + ni*16 + l15)*64 + ((kk*4 + lhi) ^ sw)*8];
      #pragma unroll
      for (int mi = 0; mi < 4; mi++)
        #pragma unroll
        for (int ni = 0; ni < NF; ni++)
          acc[mi][ni] = __builtin_amdgcn_mfma_f32_16x16x32_bf16(bb[ni], a[mi], acc[mi][ni], 0, 0, 0);
    }
    asm volatile("s_waitcnt lgkmcnt(0)" ::: "memory");    // own ds_reads done
    __builtin_amdgcn_s_barrier();                         // safe to overwrite cur
  }

  if constexpr (MODE == 0 || MODE == 2){
    // --- LDS-transpose epilogue: pack bf16 tile, then wide coalesced stores.
    // Safe to reuse As: main loop ended with lgkmcnt(0) + barrier.
    u16* tile = (u16*)&As[0][0];     // 128 rows x stride 136 elems = 34 KB
    #pragma unroll
    for (int mi = 0; mi < 4; mi++){
      int ml = wr*64 + mi*16 + l15;
      #pragma unroll
      for (int ni = 0; ni < NF; ni++){
        int nl = wc*NF*16 + ni*16 + lhi*4;
        f4 v = acc[mi][ni];
        float4 b4 = *(const float4*)(bias + n0 + nl);
        v[0] += b4.x; v[1] += b4.y; v[2] += b4.z; v[3] += b4.w;
        u32 p0, p1;
        if constexpr (MODE == 2){
          p0 = pk_bf16(gelu_f(v[0]), gelu_f(v[1]));
          p1 = pk_bf16(gelu_f(v[2]), gelu_f(v[3]));
        } else {
          p0 = pk_bf16(v[0], v[1]);
          p1 = pk_bf16(v[2], v[3]);
        }
        *(u32*)&tile[ml*136 + nl]     = p0;
        *(u32*)&tile[ml*136 + nl + 2] = p1;
      }
    }
    __syncthreads();
    // linear write-out: 16 threads per row -> 16 full 256B rows per store
    int rr = tid >> 4;            // 0..15
    int cc = (tid & 15) * 8;      // elem col 0..120
    #pragma unroll
    for (int pass = 0; pass < 8; pass++){
      int row = rr + pass*16;
      uint4 val = *(const uint4*)&tile[row*136 + cc];
      *(uint4*)((u16*)outp + ((size_t)((int)m0 + row))*N + n0 + cc) = val;
    }
  } else {
    // f32 modes: float4/lane stores already full-sector. Unchanged.
    #pragma unroll
    for (int mi = 0; mi < 4; mi++){
      int m = (int)m0 + wr*64 + mi*16 + l15;
      int src = 0;
      if constexpr (MODE == 1) src = win_to_src(m);
      #pragma unroll
      for (int ni = 0; ni < NF; ni++){
        int n = n0 + wc*NF*16 + ni*16 + lhi*4;
        f4 v = acc[mi][ni];
        float4 b4 = *(const float4*)(bias + n);
        v[0] += b4.x; v[1] += b4.y; v[2] += b4.z; v[3] += b4.w;
        if constexpr (MODE == 1){
          const float4 r4 = *(const float4*)(resid + (size_t)src*384 + n);
          float4 o4; o4.x = v[0]+r4.x; o4.y = v[1]+r4.y; o4.z = v[2]+r4.z; o4.w = v[3]+r4.w;
          *(float4*)((float*)outp + (size_t)src*384 + n) = o4;
        } else {
          float4* o = (float4*)((float*)outp + (size_t)m*N + n);
          float4 c4 = *o;
          c4.x += v[0]; c4.y += v[1]; c4.z += v[2]; c4.w += v[3];
          *o = c4;
        }
      }
    }
  }
}

// one wave per (window, head): S=QK^T (pad 49->64), +bias+mask, softmax, O=PV
// bm is bf16 (halves bias-read bytes); V loaded via b128.
__global__ __launch_bounds__(256) void attn_kernel(
    const u16* __restrict__ qkv, const u16* __restrict__ bm, u16* __restrict__ ao)
{
  const int wi = blockIdx.x;            // 0..2047
  const int hg = blockIdx.y;            // 0..2
  const int wv = threadIdx.x >> 6, lane = threadIdx.x & 63;
  const int h = hg*4 + wv;
  const int l15 = lane & 15, lhi = lane >> 4;
  const int wq = wi & 63;

  __shared__ u16 Plds[4][64*72];
  __shared__ u16 Vlds[4][32*72];

  const size_t base = (size_t)wi * 49 * 1152;
  s8v z8 = (s8v)0;

  // V -> LDS transposed: Vlds[d][n]; b128 global loads (4/lane)
  #pragma unroll
  for (int i = 0; i < 4; i++){
    int n  = i*16 + (lane >> 2);
    int d8 = (lane & 3)*8;
    s8v v = (n < 49) ? *(const s8v*)&qkv[base + (size_t)n*1152 + 768 + h*32 + d8] : z8;
    #pragma unroll
    for (int j = 0; j < 8; j++)
      Vlds[wv][(d8 + j)*72 + n] = (u16)v[j];
  }

  // Q,K fragments (hd=32 == one MFMA K-step)
  s8v aQ[4], bK[4];
  #pragma unroll
  for (int mi = 0; mi < 4; mi++){
    int rowq = mi*16 + l15;
    aQ[mi] = (rowq < 49) ? *(const s8v*)&qkv[base + (size_t)rowq*1152 +   0 + h*32 + lhi*8] : z8;
    bK[mi] = (rowq < 49) ? *(const s8v*)&qkv[base + (size_t)rowq*1152 + 384 + h*32 + lhi*8] : z8;
  }
  f4 zf = {0.f, 0.f, 0.f, 0.f};
  f4 s[4][4];
  #pragma unroll
  for (int mi = 0; mi < 4; mi++)
    #pragma unroll
    for (int ni = 0; ni < 4; ni++)
      s[mi][ni] = __builtin_amdgcn_mfma_f32_16x16x32_bf16(aQ[mi], bK[ni], zf, 0, 0, 0);

  // + rel-pos bias + shift mask (precomputed bf16, pads = -1e9)
  const u16* bmp = bm + (size_t)(wq*12 + h) * 4096;
  #pragma unroll
  for (int mi = 0; mi < 4; mi++)
    #pragma unroll
    for (int ni = 0; ni < 4; ni++)
      #pragma unroll
      for (int r = 0; r < 4; r++){
        int m = mi*16 + lhi*4 + r, n = ni*16 + l15;
        s[mi][ni][r] += bf2f(bmp[m*64 + n]);
      }

  // softmax over n: 4 in-register + 16-lane shfl_xor reduce
  #pragma unroll
  for (int mi = 0; mi < 4; mi++){
    #pragma unroll
    for (int r = 0; r < 4; r++){
      float mx = fmaxf(fmaxf(s[mi][0][r], s[mi][1][r]), fmaxf(s[mi][2][r], s[mi][3][r]));
      mx = fmaxf(mx, __shfl_xor(mx, 1));
      mx = fmaxf(mx, __shfl_xor(mx, 2));
      mx = fmaxf(mx, __shfl_xor(mx, 4));
      mx = fmaxf(mx, __shfl_xor(mx, 8));
      float sum = 0.f;
      #pragma unroll
      for (int ni = 0; ni < 4; ni++){
        float p = __expf(s[mi][ni][r] - mx);
        s[mi][ni][r] = p; sum += p;
      }
      sum += __shfl_xor(sum, 1);
      sum += __shfl_xor(sum, 2);
      sum += __shfl_xor(sum, 4);
      sum += __shfl_xor(sum, 8);
      float inv = 1.f / sum;
      #pragma unroll
      for (int ni = 0; ni < 4; ni++) s[mi][ni][r] *= inv;
    }
  }

  // P -> LDS (C-layout scatter, bf16)
  #pragma unroll
  for (int mi = 0; mi < 4; mi++)
    #pragma unroll
    for (int ni = 0; ni < 4; ni++)
      #pragma unroll
      for (int r = 0; r < 4; r++){
        int m = mi*16 + lhi*4 + r, n = ni*16 + l15;
        Plds[wv][m*72 + n] = f2bf(s[mi][ni][r]);
      }
  __syncthreads();

  // O = P @ V  (K=64 -> 2 k-steps)
  f4 o[4][2] = {};
  #pragma unroll
  for (int ks = 0; ks < 2; ks++){
    s8v aP[4], bV[2];
    #pragma unroll
    for (int mi = 0; mi < 4; mi++)
      aP[mi] = *(const s8v*)&Plds[wv][(mi*16 + l15)*72 + ks*32 + lhi*8];
    #pragma unroll
    for (int di = 0; di < 2; di++)
      bV[di] = *(const s8v*)&Vlds[wv][(di*16 + l15)*72 + ks*32 + lhi*8];
    #pragma unroll
    for (int mi = 0; mi < 4; mi++)
      #pragma unroll
      for (int di = 0; di < 2; di++)
        o[mi][di] = __builtin_amdgcn_mfma_f32_16x16x32_bf16(aP[mi], bV[di], o[mi][di], 0, 0, 0);
  }

  // store O rows < 49
  #pragma unroll
  for (int mi = 0; mi < 4; mi++)
    #pragma unroll
    for (int di = 0; di < 2; di++)
      #pragma unroll
      for (int r = 0; r < 4; r++){
        int m = mi*16 + lhi*4 + r;
        if (m < 49){
          int d = di*16 + l15;
          ao[((size_t)wi*49 + m)*384 + h*32 + d] = f2bf(o[mi][di][r]);
        }
      }
}

extern "C" void kernel_launch(void* const* d_in, const int* in_sizes, int n_in,
                              void* d_out, int out_size, void* d_ws, size_t ws_size,
                              hipStream_t stream)
{
  const float* x      = (const float*)d_in[0];
  const float* table  = (const float*)d_in[1];
  const float* qkv_w  = (const float*)d_in[2];
  const float* qkv_b  = (const float*)d_in[3];
  const float* proj_w = (const float*)d_in[4];
  const float* proj_b = (const float*)d_in[5];
  const float* n1w    = (const float*)d_in[6];
  const float* n1b    = (const float*)d_in[7];
  const float* n2w    = (const float*)d_in[8];
  const float* n2b    = (const float*)d_in[9];
  const float* w1     = (const float*)d_in[10];
  const float* b1     = (const float*)d_in[11];
  const float* w2     = (const float*)d_in[12];
  const float* b2     = (const float*)d_in[13];
  float* out = (float*)d_out;

  const size_t M = 100352;  // 32 * 3136 tokens (= 2048 windows * 49)
  const float SC = 0.17677669529663689f;  // hd^-0.5

  const size_t R1 = M * 1536 * 2;              // qkv (uses 1152 cols) | mlp hidden
  const size_t R2 = M * 384 * 2;               // ybf | ao | y2
  const size_t R3 = (size_t)64*12*64*64*2;     // biasmask (bf16)
  const size_t WT = (size_t)(1152*384 + 384*384 + 1536*384 + 384*1536) * 2;
  const size_t BB = 1152 * 4;                  // prescaled qkv bias
  const size_t needed = R1 + R2 + R3 + WT + BB;
  if (ws_size < needed){
    sentinel_kernel<<<1, 1, 0, stream>>>(out);
    return;
  }

  char* p = (char*)d_ws;
  u16*   qkvbuf = (u16*)p;                       // R1 (also mlp hidden)
  u16*   ybuf   = (u16*)(p + R1);                // R2 (ybf -> ao -> y2)
  u16*   bmbuf  = (u16*)(p + R1 + R2);           // R3
  u16*   qkvT   = (u16*)(p + R1 + R2 + R3);
  u16*   projT  = qkvT  + (size_t)1152*384;
  u16*   w1T    = projT + (size_t)384*384;
  u16*   w2T    = w1T   + (size_t)1536*384;
  float* qkvb_s = (float*)(p + R1 + R2 + R3 + WT);

  // weight transposes (K,N)->(N,K) bf16; q-scale folded into qkv rows < 384
  transpose_cast<<<dim3(24, 72),  dim3(16,16), 0, stream>>>(qkv_w,  qkvT, 384, 1152, SC, 384);
  transpose_cast<<<dim3(24, 24),  dim3(16,16), 0, stream>>>(proj_w, projT, 384, 384, 1.f, 0);
  transpose_cast<<<dim3(24, 96),  dim3(16,16), 0, stream>>>(w1,     w1T,  384, 1536, 1.f, 0);
  transpose_cast<<<dim3(96, 24),  dim3(16,16), 0, stream>>>(w2,     w2T,  1536, 384, 1.f, 0);
  scale_bias<<<5, 256, 0, stream>>>(qkv_b, qkvb_s, 1152, SC, 384);
  build_biasmask<<<dim3(64, 12), 256, 0, stream>>>(table, bmbuf);

  // LN1 with shift+window gather -> ybf (window-ordered rows)
  ln_kernel<true><<<M/4, 256, 0, stream>>>(x, n1w, n1b, ybuf, (int)M);

  // QKV GEMM: ybf @ qkv_w + b (q prescaled), bf16 out. 128-tile BK=64, gn=9
  gemm_bf16<0,4><<<784*9, 256, 0, stream>>>(ybuf, qkvT, qkvb_s, nullptr, qkvbuf, 384, 1152, 9);

  // windowed attention -> ao (overwrites ybf)
  attn_kernel<<<dim3(2048, 3), 256, 0, stream>>>(qkvbuf, bmbuf, ybuf);

  // proj GEMM + un-shift scatter + residual -> out (= x2). gn=3
  gemm_bf16<1,4><<<784*3, 256, 0, stream>>>(ybuf, projT, proj_b, x, out, 384, 384, 3);

  // LN2 -> y2 (reuses ybuf)
  ln_kernel<false><<<M/4, 256, 0, stream>>>(out, n2w, n2b, ybuf, (int)M);

  // MLP fc1 + gelu -> hidden (reuses qkvbuf region). gn=12
  gemm_bf16<2,4><<<784*12, 256, 0, stream>>>(ybuf, w1T, b1, nullptr, qkvbuf, 384, 1536, 12);

  // MLP fc2, accumulate into out (x2 + mlp). gn=3
  gemm_bf16<3,4><<<784*3, 256, 0, stream>>>(qkvbuf, w2T, b2, nullptr, out, 1536, 384, 3);
}

// Round 12
// 941.247 us; speedup vs baseline: 1.1199x; 1.0300x over previous
//
#include <hip/hip_runtime.h>

typedef unsigned short u16;
typedef unsigned int u32;
typedef short s8v __attribute__((ext_vector_type(8)));
typedef float f4 __attribute__((ext_vector_type(4)));

#define GL16(g, l) __builtin_amdgcn_global_load_lds((const __attribute__((address_space(1))) u32*)(g), (__attribute__((address_space(3))) u32*)(l), 16, 0, 0)

__device__ __forceinline__ u16 f2bf(float f){
  u32 u = __builtin_bit_cast(u32, f);
  u32 r = u + 0x7fffu + ((u >> 16) & 1u);
  return (u16)(r >> 16);
}
__device__ __forceinline__ float bf2f(u16 u){
  u32 x = ((u32)u) << 16;
  return __builtin_bit_cast(float, x);
}

// pack 2 f32 -> 2 bf16 (RNE), one instruction
__device__ __forceinline__ u32 pk_bf16(float lo, float hi){
  u32 r;
  asm("v_cvt_pk_bf16_f32 %0, %1, %2" : "=v"(r) : "v"(lo), "v"(hi));
  return r;
}

// exact-grade gelu: erf via Abramowitz-Stegun 7.1.26 (|eps|<=1.5e-7)
__device__ __forceinline__ float gelu_f(float x){
  float y = fabsf(x) * 0.70710678118654752f;
  float t = __builtin_amdgcn_rcpf(1.f + 0.3275911f*y);
  float p = ((((1.061405429f*t - 1.453152027f)*t + 1.421413741f)*t - 0.284496736f)*t + 0.254829592f)*t;
  float er = 1.f - p*__expf(-y*y);
  er = copysignf(er, x);
  return 0.5f*x*(1.f + er);
}

// window-order row (wi*49+n) -> natural token row (b*3136 + h*56 + w), shift=+3
__device__ __forceinline__ int win_to_src(int orow){
  int wi = orow / 49;
  int n  = orow - wi*49;
  int b  = wi >> 6;
  int wq = wi & 63;
  int wh = wq >> 3, ww = wq & 7;
  int r = n / 7, c = n - r*7;
  int hh = wh*7 + r + 3; if (hh >= 56) hh -= 56;
  int wp = ww*7 + c + 3; if (wp >= 56) wp -= 56;
  return (b*56 + hh)*56 + wp;
}

__global__ void sentinel_kernel(float* o){ o[0] = 1.0e9f; }

// (K,N) f32 -> (N,K) bf16; rows n < scale_lim get *scale (q-scale folding)
__global__ void transpose_cast(const float* __restrict__ in, u16* __restrict__ out,
                               int K, int N, float scale, int scale_lim){
  __shared__ float tile[16][17];
  int kb = blockIdx.x*16, nb = blockIdx.y*16;
  int tx = threadIdx.x, ty = threadIdx.y;
  int k = kb + ty, n = nb + tx;
  tile[ty][tx] = (k < K && n < N) ? in[(size_t)k*N + n] : 0.f;
  __syncthreads();
  int on = nb + ty, ok = kb + tx;
  if (on < N && ok < K){
    float v = tile[tx][ty];
    if (on < scale_lim) v *= scale;
    out[(size_t)on*K + ok] = f2bf(v);
  }
}

// prescale first `lim` entries of bias by s
__global__ void scale_bias(const float* __restrict__ in, float* __restrict__ out,
                           int n, float s, int lim){
  int i = blockIdx.x*256 + threadIdx.x;
  if (i < n) out[i] = in[i] * (i < lim ? s : 1.f);
}

// biasmask[wq][h][m][n], 64x12x64x64 BF16. m=query, n=key. -1e9 on pads.
__global__ void build_biasmask(const float* __restrict__ table, u16* __restrict__ bm){
  int wq = blockIdx.x, h = blockIdx.y;
  int wh = wq >> 3, ww = wq & 7;
  u16* o = bm + (size_t)(wq*12 + h) * 4096;
  for (int i = threadIdx.x; i < 4096; i += 256){
    int m = i >> 6, n = i & 63;
    float v;
    if (m < 49 && n < 49){
      int rm = m/7, cm = m - rm*7;
      int rn = n/7, cn = n - rn*7;
      int idx = (rm - rn + 6)*13 + (cm - cn + 6);
      v = table[idx*12 + h];
      int ym = wh*7 + rm, xm = ww*7 + cm;
      int yn = wh*7 + rn, xn = ww*7 + cn;
      int lm = (ym < 49 ? 0 : (ym < 53 ? 1 : 2))*3 + (xm < 49 ? 0 : (xm < 53 ? 1 : 2));
      int ln = (yn < 49 ? 0 : (yn < 53 ? 1 : 2))*3 + (xn < 49 ? 0 : (xn < 53 ? 1 : 2));
      if (lm != ln) v += -100.f;
    } else {
      v = -1e9f;
    }
    o[i] = f2bf(v);
  }
}

// LayerNorm over C=384, one wave per row. GATHER: row gathered via win_to_src.
template<bool GATHER>
__global__ __launch_bounds__(256) void ln_kernel(const float* __restrict__ x,
    const float* __restrict__ g, const float* __restrict__ b,
    u16* __restrict__ y, int nrows)
{
  int row = blockIdx.x*4 + (threadIdx.x >> 6);
  int lane = threadIdx.x & 63;
  if (row >= nrows) return;
  int src = GATHER ? win_to_src(row) : row;
  const float* xr = x + (size_t)src*384;
  float v[6];
  float s = 0.f, s2 = 0.f;
  #pragma unroll
  for (int p = 0; p < 3; p++){
    float2 t = *(const float2*)(xr + p*128 + lane*2);
    v[p*2] = t.x; v[p*2+1] = t.y;
    s += t.x + t.y; s2 += t.x*t.x + t.y*t.y;
  }
  #pragma unroll
  for (int off = 32; off; off >>= 1){
    s  += __shfl_xor(s,  off);
    s2 += __shfl_xor(s2, off);
  }
  float mean = s * (1.f/384.f);
  float var  = s2 * (1.f/384.f) - mean*mean;
  float rs   = rsqrtf(var + 1e-5f);
  u16* yr = y + (size_t)row*384;
  #pragma unroll
  for (int p = 0; p < 3; p++){
    int c = p*128 + lane*2;
    float a0 = (v[p*2]   - mean)*rs*g[c]   + b[c];
    float a1 = (v[p*2+1] - mean)*rs*g[c+1] + b[c+1];
    *(u32*)(yr + c) = pk_bf16(a0, a1);
  }
}

// ===========================================================================
// 128x128 GEMM, BK=32, TRIPLE-BUFFERED (prefetch depth 2).
// r12 theory: 2-buffer BK=64 is structurally depth-1 prefetch -> each K-step
// raw-stalls ~600cyc on HBM/L2 latency. BK=32 x 3 buffers: loads land 2 full
// iterations before use, LDS 48 KB -> 3 blocks/CU (12 waves: TLP too).
// Wave tile stays 64x64 (8 ds_read : 16 MFMA per step -- proven ratio).
// vmcnt ledger: 4 loads/thread/stage, <=3 stages in flight -> vmcnt(8)
// steady, 4/0 tail. stage(kt+2) overwrites buf[(kt-1)%3], safe: prior step
// ended lgkm(0)+barrier. Swizzle for 64B rows: chunk ^= (row>>1)&3 on BOTH
// stage-source and read (2-way residual = free). XCD swizzle, bn-fastest,
// operand-swapped MFMA, LDS-transpose bf16 epilogue (r11-verified).
// MODE 0: +bias, bf16 (QKV) | 1: +bias+resid scatter f32 (proj)
//      2: +bias+gelu bf16 (fc1) | 3: +bias accumulate f32 (fc2)
// ===========================================================================
template<int MODE, int NF>
__global__ __launch_bounds__(256) void gemm_bf16(
    const u16* __restrict__ A, const u16* __restrict__ Bt,
    const float* __restrict__ bias, const float* __restrict__ resid,
    void* __restrict__ outp, int K, int N, int gn)
{
  constexpr int TN = NF * 32;   // 128
  __shared__ u16 smem[6*4096];  // A bufs 0..2 at 0,4096,8192; B bufs at 12288+
  const int tid  = threadIdx.x;
  const int lane = tid & 63, wv = tid >> 6;
  const int wr = wv >> 1, wc = wv & 1;
  const int l15 = lane & 15, lhi = lane >> 4;
  const int key = (l15 >> 1) & 3;       // read-side swizzle key ((row>>1)&3)

  int total = gridDim.x;
  int flat  = blockIdx.x;
  int swz   = flat;
  if ((total & 7) == 0){
    int cpx = total >> 3;
    swz = (flat & 7)*cpx + (flat >> 3);
  }
  int bm = swz / gn, bn = swz - bm*gn;
  const size_t m0 = (size_t)bm * 128;
  const int n0 = bn * TN;

  f4 acc[4][NF] = {};

  // stage one BK=32 K-tile (2 A + 2 B GL16 per thread) into buffer `buf`
  auto stage = [&](int buf, int kt){
    #pragma unroll
    for (int it = 0; it < 2; it++){
      int c = it*256 + tid;
      int row = c >> 2;
      int col = ((c & 3) ^ ((c >> 3) & 3)) * 8;   // inverse-swizzled source
      const u16* ga = A + (m0 + (size_t)row)*K + kt*32 + col;
      GL16(ga, &smem[buf*4096 + (it*256 + wv*64)*8]);
    }
    #pragma unroll
    for (int it = 0; it < 2; it++){
      int c = it*256 + tid;
      int row = c >> 2;
      int col = ((c & 3) ^ ((c >> 3) & 3)) * 8;
      const u16* gb = Bt + ((size_t)n0 + row)*K + kt*32 + col;
      GL16(gb, &smem[12288 + buf*4096 + (it*256 + wv*64)*8]);
    }
  };

  const int nk = K >> 5;
  stage(0, 0);
  stage(1, 1);
  int cur = 0;
  for (int kt = 0; kt < nk; kt++){
    if (kt + 2 < nk){
      int nb = cur + 2; if (nb >= 3) nb -= 3;
      stage(nb, kt + 2);
      asm volatile("s_waitcnt vmcnt(8)" ::: "memory");   // cur's 4 loads landed
    } else if (kt + 1 < nk){
      asm volatile("s_waitcnt vmcnt(4)" ::: "memory");
    } else {
      asm volatile("s_waitcnt vmcnt(0)" ::: "memory");
    }
    __builtin_amdgcn_s_barrier();                         // everyone's landed

    s8v a[4], bb[NF];
    #pragma unroll
    for (int mi = 0; mi < 4; mi++)
      a[mi] = *(const s8v*)&smem[cur*4096 + (wr*64 + mi*16 + l15)*32 + ((lhi ^ key))*8];
    #pragma unroll
    for (int ni = 0; ni < NF; ni++)
      bb[ni] = *(const s8v*)&smem[12288 + cur*4096 + (wc*NF*16 + ni*16 + l15)*32 + ((lhi ^ key))*8];
    #pragma unroll
    for (int mi = 0; mi < 4; mi++)
      #pragma unroll
      for (int ni = 0; ni < NF; ni++)
        acc[mi][ni] = __builtin_amdgcn_mfma_f32_16x16x32_bf16(bb[ni], a[mi], acc[mi][ni], 0, 0, 0);

    asm volatile("s_waitcnt lgkmcnt(0)" ::: "memory");    // own ds_reads done
    __builtin_amdgcn_s_barrier();                         // buf[cur] reusable
    cur = (cur == 2) ? 0 : cur + 1;
  }

  if constexpr (MODE == 0 || MODE == 2){
    // LDS-transpose epilogue (r11): pack bf16 tile, then wide coalesced stores.
    // smem free: loop ended with lgkm(0)+barrier. 128*136 = 17408 <= 24576.
    u16* tile = smem;
    #pragma unroll
    for (int mi = 0; mi < 4; mi++){
      int ml = wr*64 + mi*16 + l15;
      #pragma unroll
      for (int ni = 0; ni < NF; ni++){
        int nl = wc*NF*16 + ni*16 + lhi*4;
        f4 v = acc[mi][ni];
        float4 b4 = *(const float4*)(bias + n0 + nl);
        v[0] += b4.x; v[1] += b4.y; v[2] += b4.z; v[3] += b4.w;
        u32 p0, p1;
        if constexpr (MODE == 2){
          p0 = pk_bf16(gelu_f(v[0]), gelu_f(v[1]));
          p1 = pk_bf16(gelu_f(v[2]), gelu_f(v[3]));
        } else {
          p0 = pk_bf16(v[0], v[1]);
          p1 = pk_bf16(v[2], v[3]);
        }
        *(u32*)&tile[ml*136 + nl]     = p0;
        *(u32*)&tile[ml*136 + nl + 2] = p1;
      }
    }
    __syncthreads();
    int rr = tid >> 4;            // 0..15
    int cc = (tid & 15) * 8;      // elem col 0..120
    #pragma unroll
    for (int pass = 0; pass < 8; pass++){
      int row = rr + pass*16;
      uint4 val = *(const uint4*)&tile[row*136 + cc];
      *(uint4*)((u16*)outp + ((size_t)((int)m0 + row))*N + n0 + cc) = val;
    }
  } else {
    // f32 modes: float4/lane stores already full-sector. Unchanged.
    #pragma unroll
    for (int mi = 0; mi < 4; mi++){
      int m = (int)m0 + wr*64 + mi*16 + l15;
      int src = 0;
      if constexpr (MODE == 1) src = win_to_src(m);
      #pragma unroll
      for (int ni = 0; ni < NF; ni++){
        int n = n0 + wc*NF*16 + ni*16 + lhi*4;
        f4 v = acc[mi][ni];
        float4 b4 = *(const float4*)(bias + n);
        v[0] += b4.x; v[1] += b4.y; v[2] += b4.z; v[3] += b4.w;
        if constexpr (MODE == 1){
          const float4 r4 = *(const float4*)(resid + (size_t)src*384 + n);
          float4 o4; o4.x = v[0]+r4.x; o4.y = v[1]+r4.y; o4.z = v[2]+r4.z; o4.w = v[3]+r4.w;
          *(float4*)((float*)outp + (size_t)src*384 + n) = o4;
        } else {
          float4* o = (float4*)((float*)outp + (size_t)m*N + n);
          float4 c4 = *o;
          c4.x += v[0]; c4.y += v[1]; c4.z += v[2]; c4.w += v[3];
          *o = c4;
        }
      }
    }
  }
}

// one wave per (window, head): S=QK^T (pad 49->64), +bias+mask, softmax, O=PV
// bm is bf16 (halves bias-read bytes); V loaded via b128.
__global__ __launch_bounds__(256) void attn_kernel(
    const u16* __restrict__ qkv, const u16* __restrict__ bm, u16* __restrict__ ao)
{
  const int wi = blockIdx.x;            // 0..2047
  const int hg = blockIdx.y;            // 0..2
  const int wv = threadIdx.x >> 6, lane = threadIdx.x & 63;
  const int h = hg*4 + wv;
  const int l15 = lane & 15, lhi = lane >> 4;
  const int wq = wi & 63;

  __shared__ u16 Plds[4][64*72];
  __shared__ u16 Vlds[4][32*72];

  const size_t base = (size_t)wi * 49 * 1152;
  s8v z8 = (s8v)0;

  // V -> LDS transposed: Vlds[d][n]; b128 global loads (4/lane)
  #pragma unroll
  for (int i = 0; i < 4; i++){
    int n  = i*16 + (lane >> 2);
    int d8 = (lane & 3)*8;
    s8v v = (n < 49) ? *(const s8v*)&qkv[base + (size_t)n*1152 + 768 + h*32 + d8] : z8;
    #pragma unroll
    for (int j = 0; j < 8; j++)
      Vlds[wv][(d8 + j)*72 + n] = (u16)v[j];
  }

  // Q,K fragments (hd=32 == one MFMA K-step)
  s8v aQ[4], bK[4];
  #pragma unroll
  for (int mi = 0; mi < 4; mi++){
    int rowq = mi*16 + l15;
    aQ[mi] = (rowq < 49) ? *(const s8v*)&qkv[base + (size_t)rowq*1152 +   0 + h*32 + lhi*8] : z8;
    bK[mi] = (rowq < 49) ? *(const s8v*)&qkv[base + (size_t)rowq*1152 + 384 + h*32 + lhi*8] : z8;
  }
  f4 zf = {0.f, 0.f, 0.f, 0.f};
  f4 s[4][4];
  #pragma unroll
  for (int mi = 0; mi < 4; mi++)
    #pragma unroll
    for (int ni = 0; ni < 4; ni++)
      s[mi][ni] = __builtin_amdgcn_mfma_f32_16x16x32_bf16(aQ[mi], bK[ni], zf, 0, 0, 0);

  // + rel-pos bias + shift mask (precomputed bf16, pads = -1e9)
  const u16* bmp = bm + (size_t)(wq*12 + h) * 4096;
  #pragma unroll
  for (int mi = 0; mi < 4; mi++)
    #pragma unroll
    for (int ni = 0; ni < 4; ni++)
      #pragma unroll
      for (int r = 0; r < 4; r++){
        int m = mi*16 + lhi*4 + r, n = ni*16 + l15;
        s[mi][ni][r] += bf2f(bmp[m*64 + n]);
      }

  // softmax over n: 4 in-register + 16-lane shfl_xor reduce
  #pragma unroll
  for (int mi = 0; mi < 4; mi++){
    #pragma unroll
    for (int r = 0; r < 4; r++){
      float mx = fmaxf(fmaxf(s[mi][0][r], s[mi][1][r]), fmaxf(s[mi][2][r], s[mi][3][r]));
      mx = fmaxf(mx, __shfl_xor(mx, 1));
      mx = fmaxf(mx, __shfl_xor(mx, 2));
      mx = fmaxf(mx, __shfl_xor(mx, 4));
      mx = fmaxf(mx, __shfl_xor(mx, 8));
      float sum = 0.f;
      #pragma unroll
      for (int ni = 0; ni < 4; ni++){
        float p = __expf(s[mi][ni][r] - mx);
        s[mi][ni][r] = p; sum += p;
      }
      sum += __shfl_xor(sum, 1);
      sum += __shfl_xor(sum, 2);
      sum += __shfl_xor(sum, 4);
      sum += __shfl_xor(sum, 8);
      float inv = 1.f / sum;
      #pragma unroll
      for (int ni = 0; ni < 4; ni++) s[mi][ni][r] *= inv;
    }
  }

  // P -> LDS (C-layout scatter, bf16)
  #pragma unroll
  for (int mi = 0; mi < 4; mi++)
    #pragma unroll
    for (int ni = 0; ni < 4; ni++)
      #pragma unroll
      for (int r = 0; r < 4; r++){
        int m = mi*16 + lhi*4 + r, n = ni*16 + l15;
        Plds[wv][m*72 + n] = f2bf(s[mi][ni][r]);
      }
  __syncthreads();

  // O = P @ V  (K=64 -> 2 k-steps)
  f4 o[4][2] = {};
  #pragma unroll
  for (int ks = 0; ks < 2; ks++){
    s8v aP[4], bV[2];
    #pragma unroll
    for (int mi = 0; mi < 4; mi++)
      aP[mi] = *(const s8v*)&Plds[wv][(mi*16 + l15)*72 + ks*32 + lhi*8];
    #pragma unroll
    for (int di = 0; di < 2; di++)
      bV[di] = *(const s8v*)&Vlds[wv][(di*16 + l15)*72 + ks*32 + lhi*8];
    #pragma unroll
    for (int mi = 0; mi < 4; mi++)
      #pragma unroll
      for (int di = 0; di < 2; di++)
        o[mi][di] = __builtin_amdgcn_mfma_f32_16x16x32_bf16(aP[mi], bV[di], o[mi][di], 0, 0, 0);
  }

  // store O rows < 49
  #pragma unroll
  for (int mi = 0; mi < 4; mi++)
    #pragma unroll
    for (int di = 0; di < 2; di++)
      #pragma unroll
      for (int r = 0; r < 4; r++){
        int m = mi*16 + lhi*4 + r;
        if (m < 49){
          int d = di*16 + l15;
          ao[((size_t)wi*49 + m)*384 + h*32 + d] = f2bf(o[mi][di][r]);
        }
      }
}

extern "C" void kernel_launch(void* const* d_in, const int* in_sizes, int n_in,
                              void* d_out, int out_size, void* d_ws, size_t ws_size,
                              hipStream_t stream)
{
  const float* x      = (const float*)d_in[0];
  const float* table  = (const float*)d_in[1];
  const float* qkv_w  = (const float*)d_in[2];
  const float* qkv_b  = (const float*)d_in[3];
  const float* proj_w = (const float*)d_in[4];
  const float* proj_b = (const float*)d_in[5];
  const float* n1w    = (const float*)d_in[6];
  const float* n1b    = (const float*)d_in[7];
  const float* n2w    = (const float*)d_in[8];
  const float* n2b    = (const float*)d_in[9];
  const float* w1     = (const float*)d_in[10];
  const float* b1     = (const float*)d_in[11];
  const float* w2     = (const float*)d_in[12];
  const float* b2     = (const float*)d_in[13];
  float* out = (float*)d_out;

  const size_t M = 100352;  // 32 * 3136 tokens (= 2048 windows * 49)
  const float SC = 0.17677669529663689f;  // hd^-0.5

  const size_t R1 = M * 1536 * 2;              // qkv (uses 1152 cols) | mlp hidden
  const size_t R2 = M * 384 * 2;               // ybf | ao | y2
  const size_t R3 = (size_t)64*12*64*64*2;     // biasmask (bf16)
  const size_t WT = (size_t)(1152*384 + 384*384 + 1536*384 + 384*1536) * 2;
  const size_t BB = 1152 * 4;                  // prescaled qkv bias
  const size_t needed = R1 + R2 + R3 + WT + BB;
  if (ws_size < needed){
    sentinel_kernel<<<1, 1, 0, stream>>>(out);
    return;
  }

  char* p = (char*)d_ws;
  u16*   qkvbuf = (u16*)p;                       // R1 (also mlp hidden)
  u16*   ybuf   = (u16*)(p + R1);                // R2 (ybf -> ao -> y2)
  u16*   bmbuf  = (u16*)(p + R1 + R2);           // R3
  u16*   qkvT   = (u16*)(p + R1 + R2 + R3);
  u16*   projT  = qkvT  + (size_t)1152*384;
  u16*   w1T    = projT + (size_t)384*384;
  u16*   w2T    = w1T   + (size_t)1536*384;
  float* qkvb_s = (float*)(p + R1 + R2 + R3 + WT);

  // weight transposes (K,N)->(N,K) bf16; q-scale folded into qkv rows < 384
  transpose_cast<<<dim3(24, 72),  dim3(16,16), 0, stream>>>(qkv_w,  qkvT, 384, 1152, SC, 384);
  transpose_cast<<<dim3(24, 24),  dim3(16,16), 0, stream>>>(proj_w, projT, 384, 384, 1.f, 0);
  transpose_cast<<<dim3(24, 96),  dim3(16,16), 0, stream>>>(w1,     w1T,  384, 1536, 1.f, 0);
  transpose_cast<<<dim3(96, 24),  dim3(16,16), 0, stream>>>(w2,     w2T,  1536, 384, 1.f, 0);
  scale_bias<<<5, 256, 0, stream>>>(qkv_b, qkvb_s, 1152, SC, 384);
  build_biasmask<<<dim3(64, 12), 256, 0, stream>>>(table, bmbuf);

  // LN1 with shift+window gather -> ybf (window-ordered rows)
  ln_kernel<true><<<M/4, 256, 0, stream>>>(x, n1w, n1b, ybuf, (int)M);

  // QKV GEMM: ybf @ qkv_w + b (q prescaled), bf16 out. BK=32 3-buf, gn=9
  gemm_bf16<0,4><<<784*9, 256, 0, stream>>>(ybuf, qkvT, qkvb_s, nullptr, qkvbuf, 384, 1152, 9);

  // windowed attention -> ao (overwrites ybf)
  attn_kernel<<<dim3(2048, 3), 256, 0, stream>>>(qkvbuf, bmbuf, ybuf);

  // proj GEMM + un-shift scatter + residual -> out (= x2). gn=3
  gemm_bf16<1,4><<<784*3, 256, 0, stream>>>(ybuf, projT, proj_b, x, out, 384, 384, 3);

  // LN2 -> y2 (reuses ybuf)
  ln_kernel<false><<<M/4, 256, 0, stream>>>(out, n2w, n2b, ybuf, (int)M);

  // MLP fc1 + gelu -> hidden (reuses qkvbuf region). gn=12
  gemm_bf16<2,4><<<784*12, 256, 0, stream>>>(ybuf, w1T, b1, nullptr, qkvbuf, 384, 1536, 12);

  // MLP fc2, accumulate into out (x2 + mlp). gn=3
  gemm_bf16<3,4><<<784*3, 256, 0, stream>>>(qkvbuf, w2T, b2, nullptr, out, 1536, 384, 3);
}

// Round 13
// 890.702 us; speedup vs baseline: 1.1834x; 1.0567x over previous
//
#include <hip/hip_runtime.h>

typedef unsigned short u16;
typedef unsigned int u32;
typedef short s8v __attribute__((ext_vector_type(8)));
typedef float f4 __attribute__((ext_vector_type(4)));

#define GL16(g, l) __builtin_amdgcn_global_load_lds((const __attribute__((address_space(1))) u32*)(g), (__attribute__((address_space(3))) u32*)(l), 16, 0, 0)

__device__ __forceinline__ u16 f2bf(float f){
  u32 u = __builtin_bit_cast(u32, f);
  u32 r = u + 0x7fffu + ((u >> 16) & 1u);
  return (u16)(r >> 16);
}
__device__ __forceinline__ float bf2f(u16 u){
  u32 x = ((u32)u) << 16;
  return __builtin_bit_cast(float, x);
}

// pack 2 f32 -> 2 bf16 (RNE), one instruction
__device__ __forceinline__ u32 pk_bf16(float lo, float hi){
  u32 r;
  asm("v_cvt_pk_bf16_f32 %0, %1, %2" : "=v"(r) : "v"(lo), "v"(hi));
  return r;
}

// exact-grade gelu: erf via Abramowitz-Stegun 7.1.26 (|eps|<=1.5e-7)
__device__ __forceinline__ float gelu_f(float x){
  float y = fabsf(x) * 0.70710678118654752f;
  float t = __builtin_amdgcn_rcpf(1.f + 0.3275911f*y);
  float p = ((((1.061405429f*t - 1.453152027f)*t + 1.421413741f)*t - 0.284496736f)*t + 0.254829592f)*t;
  float er = 1.f - p*__expf(-y*y);
  er = copysignf(er, x);
  return 0.5f*x*(1.f + er);
}

// window-order row (wi*49+n) -> natural token row (b*3136 + h*56 + w), shift=+3
__device__ __forceinline__ int win_to_src(int orow){
  int wi = orow / 49;
  int n  = orow - wi*49;
  int b  = wi >> 6;
  int wq = wi & 63;
  int wh = wq >> 3, ww = wq & 7;
  int r = n / 7, c = n - r*7;
  int hh = wh*7 + r + 3; if (hh >= 56) hh -= 56;
  int wp = ww*7 + c + 3; if (wp >= 56) wp -= 56;
  return (b*56 + hh)*56 + wp;
}

__global__ void sentinel_kernel(float* o){ o[0] = 1.0e9f; }

// (K,N) f32 -> (N,K) bf16; rows n < scale_lim get *scale (q-scale folding)
__global__ void transpose_cast(const float* __restrict__ in, u16* __restrict__ out,
                               int K, int N, float scale, int scale_lim){
  __shared__ float tile[16][17];
  int kb = blockIdx.x*16, nb = blockIdx.y*16;
  int tx = threadIdx.x, ty = threadIdx.y;
  int k = kb + ty, n = nb + tx;
  tile[ty][tx] = (k < K && n < N) ? in[(size_t)k*N + n] : 0.f;
  __syncthreads();
  int on = nb + ty, ok = kb + tx;
  if (on < N && ok < K){
    float v = tile[tx][ty];
    if (on < scale_lim) v *= scale;
    out[(size_t)on*K + ok] = f2bf(v);
  }
}

// prescale first `lim` entries of bias by s
__global__ void scale_bias(const float* __restrict__ in, float* __restrict__ out,
                           int n, float s, int lim){
  int i = blockIdx.x*256 + threadIdx.x;
  if (i < n) out[i] = in[i] * (i < lim ? s : 1.f);
}

// biasmask[wq][h][m][n], 64x12x64x64 BF16. m=query, n=key. -1e9 on pads.
__global__ void build_biasmask(const float* __restrict__ table, u16* __restrict__ bm){
  int wq = blockIdx.x, h = blockIdx.y;
  int wh = wq >> 3, ww = wq & 7;
  u16* o = bm + (size_t)(wq*12 + h) * 4096;
  for (int i = threadIdx.x; i < 4096; i += 256){
    int m = i >> 6, n = i & 63;
    float v;
    if (m < 49 && n < 49){
      int rm = m/7, cm = m - rm*7;
      int rn = n/7, cn = n - rn*7;
      int idx = (rm - rn + 6)*13 + (cm - cn + 6);
      v = table[idx*12 + h];
      int ym = wh*7 + rm, xm = ww*7 + cm;
      int yn = wh*7 + rn, xn = ww*7 + cn;
      int lm = (ym < 49 ? 0 : (ym < 53 ? 1 : 2))*3 + (xm < 49 ? 0 : (xm < 53 ? 1 : 2));
      int ln = (yn < 49 ? 0 : (yn < 53 ? 1 : 2))*3 + (xn < 49 ? 0 : (xn < 53 ? 1 : 2));
      if (lm != ln) v += -100.f;
    } else {
      v = -1e9f;
    }
    o[i] = f2bf(v);
  }
}

// LayerNorm over C=384, one wave per row. GATHER: row gathered via win_to_src.
template<bool GATHER>
__global__ __launch_bounds__(256) void ln_kernel(const float* __restrict__ x,
    const float* __restrict__ g, const float* __restrict__ b,
    u16* __restrict__ y, int nrows)
{
  int row = blockIdx.x*4 + (threadIdx.x >> 6);
  int lane = threadIdx.x & 63;
  if (row >= nrows) return;
  int src = GATHER ? win_to_src(row) : row;
  const float* xr = x + (size_t)src*384;
  float v[6];
  float s = 0.f, s2 = 0.f;
  #pragma unroll
  for (int p = 0; p < 3; p++){
    float2 t = *(const float2*)(xr + p*128 + lane*2);
    v[p*2] = t.x; v[p*2+1] = t.y;
    s += t.x + t.y; s2 += t.x*t.x + t.y*t.y;
  }
  #pragma unroll
  for (int off = 32; off; off >>= 1){
    s  += __shfl_xor(s,  off);
    s2 += __shfl_xor(s2, off);
  }
  float mean = s * (1.f/384.f);
  float var  = s2 * (1.f/384.f) - mean*mean;
  float rs   = rsqrtf(var + 1e-5f);
  u16* yr = y + (size_t)row*384;
  #pragma unroll
  for (int p = 0; p < 3; p++){
    int c = p*128 + lane*2;
    float a0 = (v[p*2]   - mean)*rs*g[c]   + b[c];
    float a1 = (v[p*2+1] - mean)*rs*g[c+1] + b[c+1];
    *(u32*)(yr + c) = pk_bf16(a0, a1);
  }
}

// ===========================================================================
// 256x128 GEMM, BK=32, 3-buffer, ONE barrier per K-step.
// r13 theory: r4-r12 plateau (~21% MfmaUtil) = per-step sync overhead + LDS
// read traffic. Fix both: wave tile 128x64 (4 waves 2Mx2N over 256x128;
// FLOP/LDS-byte 32->42.7; 12 ds_read : 32 MFMA per step) and single-barrier
// step (3 buffers make the end-of-step barrier redundant when stage is
// issued AFTER the top barrier):
//   step kt: vmcnt(6 | 0 tail) -> lgkm(0) -> barrier -> stage(kt+2) ->
//            ds_read buf[kt%3] -> 32 MFMA.
// Hazard ledger: stage(kt+2) overwrites buf[(kt-1)%3]; every wave's kt-1
// reads are covered by its own lgkm(0) before the shared barrier. vmcnt:
// 6 GL16/stage, 2 stages in flight -> vmcnt(6) proves cur landed.
// 128 MFMAs per barrier (4x r12). LDS 72KB -> 2 blocks/CU. acc 128 VGPR,
// launch_bounds(256,2) caps at 256.
// T2 swizzle (64B rows, key=(row>>1)&3 both sides), bijective XCD swizzle,
// bn-fastest, operand-swapped MFMA, LDS-transpose bf16 epilogue (r11).
// Post-loop barrier before tile reuse (tile overlaps buf2).
// MODE 0: +bias, bf16 (QKV) | 1: +bias+resid scatter f32 (proj)
//      2: +bias+gelu bf16 (fc1) | 3: +bias accumulate f32 (fc2)
// ===========================================================================
template<int MODE>
__global__ __launch_bounds__(256, 2) void gemm_bf16(
    const u16* __restrict__ A, const u16* __restrict__ Bt,
    const float* __restrict__ bias, const float* __restrict__ resid,
    void* __restrict__ outp, int K, int N, int gn)
{
  __shared__ u16 smem[36864];   // A bufs: 3 x 8192 elems @0; B bufs: 3 x 4096 @24576
  const int tid  = threadIdx.x;
  const int lane = tid & 63, wv = tid >> 6;
  const int wm = wv >> 1, wn = wv & 1;
  const int l15 = lane & 15, lhi = lane >> 4;
  const int key = (l15 >> 1) & 3;       // read-side swizzle key ((row>>1)&3)

  int total = gridDim.x;
  int flat  = blockIdx.x;
  int swz   = flat;
  if ((total & 7) == 0){
    int cpx = total >> 3;
    swz = (flat & 7)*cpx + (flat >> 3);
  }
  int bm = swz / gn, bn = swz - bm*gn;
  const size_t m0 = (size_t)bm * 256;
  const int n0 = bn * 128;

  f4 acc[8][4] = {};

  // stage one BK=32 K-tile (4 A + 2 B GL16 per thread) into buffer `buf`
  auto stage = [&](int buf, int kt){
    #pragma unroll
    for (int it = 0; it < 4; it++){
      int c = it*256 + tid;
      int row = c >> 2;
      int col = ((c & 3) ^ ((c >> 3) & 3)) * 8;   // inverse-swizzled source
      const u16* ga = A + (m0 + (size_t)row)*K + kt*32 + col;
      GL16(ga, &smem[buf*8192 + (it*256 + wv*64)*8]);
    }
    #pragma unroll
    for (int it = 0; it < 2; it++){
      int c = it*256 + tid;
      int row = c >> 2;
      int col = ((c & 3) ^ ((c >> 3) & 3)) * 8;
      const u16* gb = Bt + ((size_t)n0 + row)*K + kt*32 + col;
      GL16(gb, &smem[24576 + buf*4096 + (it*256 + wv*64)*8]);
    }
  };

  const int nk = K >> 5;
  stage(0, 0);
  stage(1, 1);
  int cur = 0;
  for (int kt = 0; kt < nk; kt++){
    if (kt + 1 < nk){
      asm volatile("s_waitcnt vmcnt(6)" ::: "memory");   // cur's 6 loads landed
    } else {
      asm volatile("s_waitcnt vmcnt(0)" ::: "memory");
    }
    asm volatile("s_waitcnt lgkmcnt(0)" ::: "memory");   // prev-step reads done
    __builtin_amdgcn_s_barrier();
    if (kt + 2 < nk){
      int nb = cur + 2; if (nb >= 3) nb -= 3;
      stage(nb, kt + 2);
    }

    s8v a[8], bb[4];
    #pragma unroll
    for (int mi = 0; mi < 8; mi++)
      a[mi] = *(const s8v*)&smem[cur*8192 + (wm*128 + mi*16 + l15)*32 + ((lhi ^ key))*8];
    #pragma unroll
    for (int ni = 0; ni < 4; ni++)
      bb[ni] = *(const s8v*)&smem[24576 + cur*4096 + (wn*64 + ni*16 + l15)*32 + ((lhi ^ key))*8];
    #pragma unroll
    for (int mi = 0; mi < 8; mi++)
      #pragma unroll
      for (int ni = 0; ni < 4; ni++)
        acc[mi][ni] = __builtin_amdgcn_mfma_f32_16x16x32_bf16(bb[ni], a[mi], acc[mi][ni], 0, 0, 0);

    cur = (cur == 2) ? 0 : cur + 1;
  }

  if constexpr (MODE == 0 || MODE == 2){
    // LDS-transpose epilogue: pack bf16 tile, then wide coalesced stores.
    // tile (256x136 = 69.6KB) overlaps live buffers -> barrier first.
    asm volatile("s_waitcnt lgkmcnt(0)" ::: "memory");
    __builtin_amdgcn_s_barrier();
    u16* tile = smem;
    #pragma unroll
    for (int mi = 0; mi < 8; mi++){
      int ml = wm*128 + mi*16 + l15;
      #pragma unroll
      for (int ni = 0; ni < 4; ni++){
        int nl = wn*64 + ni*16 + lhi*4;
        f4 v = acc[mi][ni];
        float4 b4 = *(const float4*)(bias + n0 + nl);
        v[0] += b4.x; v[1] += b4.y; v[2] += b4.z; v[3] += b4.w;
        u32 p0, p1;
        if constexpr (MODE == 2){
          p0 = pk_bf16(gelu_f(v[0]), gelu_f(v[1]));
          p1 = pk_bf16(gelu_f(v[2]), gelu_f(v[3]));
        } else {
          p0 = pk_bf16(v[0], v[1]);
          p1 = pk_bf16(v[2], v[3]);
        }
        *(u32*)&tile[ml*136 + nl]     = p0;
        *(u32*)&tile[ml*136 + nl + 2] = p1;
      }
    }
    __syncthreads();
    int rr = tid >> 4;            // 0..15
    int cc = (tid & 15) * 8;      // elem col 0..120
    #pragma unroll
    for (int pass = 0; pass < 16; pass++){
      int row = rr + pass*16;
      uint4 val = *(const uint4*)&tile[row*136 + cc];
      *(uint4*)((u16*)outp + ((size_t)((int)m0 + row))*N + n0 + cc) = val;
    }
  } else {
    // f32 modes: float4/lane stores already full-sector.
    #pragma unroll
    for (int mi = 0; mi < 8; mi++){
      int m = (int)m0 + wm*128 + mi*16 + l15;
      int src = 0;
      if constexpr (MODE == 1) src = win_to_src(m);
      #pragma unroll
      for (int ni = 0; ni < 4; ni++){
        int n = n0 + wn*64 + ni*16 + lhi*4;
        f4 v = acc[mi][ni];
        float4 b4 = *(const float4*)(bias + n);
        v[0] += b4.x; v[1] += b4.y; v[2] += b4.z; v[3] += b4.w;
        if constexpr (MODE == 1){
          const float4 r4 = *(const float4*)(resid + (size_t)src*384 + n);
          float4 o4; o4.x = v[0]+r4.x; o4.y = v[1]+r4.y; o4.z = v[2]+r4.z; o4.w = v[3]+r4.w;
          *(float4*)((float*)outp + (size_t)src*384 + n) = o4;
        } else {
          float4* o = (float4*)((float*)outp + (size_t)m*N + n);
          float4 c4 = *o;
          c4.x += v[0]; c4.y += v[1]; c4.z += v[2]; c4.w += v[3];
          *o = c4;
        }
      }
    }
  }
}

// one wave per (window, head): S=QK^T (pad 49->64), +bias+mask, softmax, O=PV
// bm is bf16 (halves bias-read bytes); V loaded via b128.
__global__ __launch_bounds__(256) void attn_kernel(
    const u16* __restrict__ qkv, const u16* __restrict__ bm, u16* __restrict__ ao)
{
  const int wi = blockIdx.x;            // 0..2047
  const int hg = blockIdx.y;            // 0..2
  const int wv = threadIdx.x >> 6, lane = threadIdx.x & 63;
  const int h = hg*4 + wv;
  const int l15 = lane & 15, lhi = lane >> 4;
  const int wq = wi & 63;

  __shared__ u16 Plds[4][64*72];
  __shared__ u16 Vlds[4][32*72];

  const size_t base = (size_t)wi * 49 * 1152;
  s8v z8 = (s8v)0;

  // V -> LDS transposed: Vlds[d][n]; b128 global loads (4/lane)
  #pragma unroll
  for (int i = 0; i < 4; i++){
    int n  = i*16 + (lane >> 2);
    int d8 = (lane & 3)*8;
    s8v v = (n < 49) ? *(const s8v*)&qkv[base + (size_t)n*1152 + 768 + h*32 + d8] : z8;
    #pragma unroll
    for (int j = 0; j < 8; j++)
      Vlds[wv][(d8 + j)*72 + n] = (u16)v[j];
  }

  // Q,K fragments (hd=32 == one MFMA K-step)
  s8v aQ[4], bK[4];
  #pragma unroll
  for (int mi = 0; mi < 4; mi++){
    int rowq = mi*16 + l15;
    aQ[mi] = (rowq < 49) ? *(const s8v*)&qkv[base + (size_t)rowq*1152 +   0 + h*32 + lhi*8] : z8;
    bK[mi] = (rowq < 49) ? *(const s8v*)&qkv[base + (size_t)rowq*1152 + 384 + h*32 + lhi*8] : z8;
  }
  f4 zf = {0.f, 0.f, 0.f, 0.f};
  f4 s[4][4];
  #pragma unroll
  for (int mi = 0; mi < 4; mi++)
    #pragma unroll
    for (int ni = 0; ni < 4; ni++)
      s[mi][ni] = __builtin_amdgcn_mfma_f32_16x16x32_bf16(aQ[mi], bK[ni], zf, 0, 0, 0);

  // + rel-pos bias + shift mask (precomputed bf16, pads = -1e9)
  const u16* bmp = bm + (size_t)(wq*12 + h) * 4096;
  #pragma unroll
  for (int mi = 0; mi < 4; mi++)
    #pragma unroll
    for (int ni = 0; ni < 4; ni++)
      #pragma unroll
      for (int r = 0; r < 4; r++){
        int m = mi*16 + lhi*4 + r, n = ni*16 + l15;
        s[mi][ni][r] += bf2f(bmp[m*64 + n]);
      }

  // softmax over n: 4 in-register + 16-lane shfl_xor reduce
  #pragma unroll
  for (int mi = 0; mi < 4; mi++){
    #pragma unroll
    for (int r = 0; r < 4; r++){
      float mx = fmaxf(fmaxf(s[mi][0][r], s[mi][1][r]), fmaxf(s[mi][2][r], s[mi][3][r]));
      mx = fmaxf(mx, __shfl_xor(mx, 1));
      mx = fmaxf(mx, __shfl_xor(mx, 2));
      mx = fmaxf(mx, __shfl_xor(mx, 4));
      mx = fmaxf(mx, __shfl_xor(mx, 8));
      float sum = 0.f;
      #pragma unroll
      for (int ni = 0; ni < 4; ni++){
        float p = __expf(s[mi][ni][r] - mx);
        s[mi][ni][r] = p; sum += p;
      }
      sum += __shfl_xor(sum, 1);
      sum += __shfl_xor(sum, 2);
      sum += __shfl_xor(sum, 4);
      sum += __shfl_xor(sum, 8);
      float inv = 1.f / sum;
      #pragma unroll
      for (int ni = 0; ni < 4; ni++) s[mi][ni][r] *= inv;
    }
  }

  // P -> LDS (C-layout scatter, bf16)
  #pragma unroll
  for (int mi = 0; mi < 4; mi++)
    #pragma unroll
    for (int ni = 0; ni < 4; ni++)
      #pragma unroll
      for (int r = 0; r < 4; r++){
        int m = mi*16 + lhi*4 + r, n = ni*16 + l15;
        Plds[wv][m*72 + n] = f2bf(s[mi][ni][r]);
      }
  __syncthreads();

  // O = P @ V  (K=64 -> 2 k-steps)
  f4 o[4][2] = {};
  #pragma unroll
  for (int ks = 0; ks < 2; ks++){
    s8v aP[4], bV[2];
    #pragma unroll
    for (int mi = 0; mi < 4; mi++)
      aP[mi] = *(const s8v*)&Plds[wv][(mi*16 + l15)*72 + ks*32 + lhi*8];
    #pragma unroll
    for (int di = 0; di < 2; di++)
      bV[di] = *(const s8v*)&Vlds[wv][(di*16 + l15)*72 + ks*32 + lhi*8];
    #pragma unroll
    for (int mi = 0; mi < 4; mi++)
      #pragma unroll
      for (int di = 0; di < 2; di++)
        o[mi][di] = __builtin_amdgcn_mfma_f32_16x16x32_bf16(aP[mi], bV[di], o[mi][di], 0, 0, 0);
  }

  // store O rows < 49
  #pragma unroll
  for (int mi = 0; mi < 4; mi++)
    #pragma unroll
    for (int di = 0; di < 2; di++)
      #pragma unroll
      for (int r = 0; r < 4; r++){
        int m = mi*16 + lhi*4 + r;
        if (m < 49){
          int d = di*16 + l15;
          ao[((size_t)wi*49 + m)*384 + h*32 + d] = f2bf(o[mi][di][r]);
        }
      }
}

extern "C" void kernel_launch(void* const* d_in, const int* in_sizes, int n_in,
                              void* d_out, int out_size, void* d_ws, size_t ws_size,
                              hipStream_t stream)
{
  const float* x      = (const float*)d_in[0];
  const float* table  = (const float*)d_in[1];
  const float* qkv_w  = (const float*)d_in[2];
  const float* qkv_b  = (const float*)d_in[3];
  const float* proj_w = (const float*)d_in[4];
  const float* proj_b = (const float*)d_in[5];
  const float* n1w    = (const float*)d_in[6];
  const float* n1b    = (const float*)d_in[7];
  const float* n2w    = (const float*)d_in[8];
  const float* n2b    = (const float*)d_in[9];
  const float* w1     = (const float*)d_in[10];
  const float* b1     = (const float*)d_in[11];
  const float* w2     = (const float*)d_in[12];
  const float* b2     = (const float*)d_in[13];
  float* out = (float*)d_out;

  const size_t M = 100352;  // 32 * 3136 tokens (= 2048 windows * 49)
  const float SC = 0.17677669529663689f;  // hd^-0.5

  const size_t R1 = M * 1536 * 2;              // qkv (uses 1152 cols) | mlp hidden
  const size_t R2 = M * 384 * 2;               // ybf | ao | y2
  const size_t R3 = (size_t)64*12*64*64*2;     // biasmask (bf16)
  const size_t WT = (size_t)(1152*384 + 384*384 + 1536*384 + 384*1536) * 2;
  const size_t BB = 1152 * 4;                  // prescaled qkv bias
  const size_t needed = R1 + R2 + R3 + WT + BB;
  if (ws_size < needed){
    sentinel_kernel<<<1, 1, 0, stream>>>(out);
    return;
  }

  char* p = (char*)d_ws;
  u16*   qkvbuf = (u16*)p;                       // R1 (also mlp hidden)
  u16*   ybuf   = (u16*)(p + R1);                // R2 (ybf -> ao -> y2)
  u16*   bmbuf  = (u16*)(p + R1 + R2);           // R3
  u16*   qkvT   = (u16*)(p + R1 + R2 + R3);
  u16*   projT  = qkvT  + (size_t)1152*384;
  u16*   w1T    = projT + (size_t)384*384;
  u16*   w2T    = w1T   + (size_t)1536*384;
  float* qkvb_s = (float*)(p + R1 + R2 + R3 + WT);

  // weight transposes (K,N)->(N,K) bf16; q-scale folded into qkv rows < 384
  transpose_cast<<<dim3(24, 72),  dim3(16,16), 0, stream>>>(qkv_w,  qkvT, 384, 1152, SC, 384);
  transpose_cast<<<dim3(24, 24),  dim3(16,16), 0, stream>>>(proj_w, projT, 384, 384, 1.f, 0);
  transpose_cast<<<dim3(24, 96),  dim3(16,16), 0, stream>>>(w1,     w1T,  384, 1536, 1.f, 0);
  transpose_cast<<<dim3(96, 24),  dim3(16,16), 0, stream>>>(w2,     w2T,  1536, 384, 1.f, 0);
  scale_bias<<<5, 256, 0, stream>>>(qkv_b, qkvb_s, 1152, SC, 384);
  build_biasmask<<<dim3(64, 12), 256, 0, stream>>>(table, bmbuf);

  // LN1 with shift+window gather -> ybf (window-ordered rows)
  ln_kernel<true><<<M/4, 256, 0, stream>>>(x, n1w, n1b, ybuf, (int)M);

  // QKV GEMM: ybf @ qkv_w + b (q prescaled), bf16 out. 256x128 tile, gn=9
  gemm_bf16<0><<<392*9, 256, 0, stream>>>(ybuf, qkvT, qkvb_s, nullptr, qkvbuf, 384, 1152, 9);

  // windowed attention -> ao (overwrites ybf)
  attn_kernel<<<dim3(2048, 3), 256, 0, stream>>>(qkvbuf, bmbuf, ybuf);

  // proj GEMM + un-shift scatter + residual -> out (= x2). gn=3
  gemm_bf16<1><<<392*3, 256, 0, stream>>>(ybuf, projT, proj_b, x, out, 384, 384, 3);

  // LN2 -> y2 (reuses ybuf)
  ln_kernel<false><<<M/4, 256, 0, stream>>>(out, n2w, n2b, ybuf, (int)M);

  // MLP fc1 + gelu -> hidden (reuses qkvbuf region). gn=12
  gemm_bf16<2><<<392*12, 256, 0, stream>>>(ybuf, w1T, b1, nullptr, qkvbuf, 384, 1536, 12);

  // MLP fc2, accumulate into out (x2 + mlp). gn=3
  gemm_bf16<3><<<392*3, 256, 0, stream>>>(qkvbuf, w2T, b2, nullptr, out, 1536, 384, 3);
}

// Round 14
// 888.134 us; speedup vs baseline: 1.1868x; 1.0029x over previous
//
#include <hip/hip_runtime.h>

typedef unsigned short u16;
typedef unsigned int u32;
typedef short s8v __attribute__((ext_vector_type(8)));
typedef float f4 __attribute__((ext_vector_type(4)));

#define GL16(g, l) __builtin_amdgcn_global_load_lds((const __attribute__((address_space(1))) u32*)(g), (__attribute__((address_space(3))) u32*)(l), 16, 0, 0)

__device__ __forceinline__ u16 f2bf(float f){
  u32 u = __builtin_bit_cast(u32, f);
  u32 r = u + 0x7fffu + ((u >> 16) & 1u);
  return (u16)(r >> 16);
}
__device__ __forceinline__ float bf2f(u16 u){
  u32 x = ((u32)u) << 16;
  return __builtin_bit_cast(float, x);
}

// pack 2 f32 -> 2 bf16 (RNE), one instruction
__device__ __forceinline__ u32 pk_bf16(float lo, float hi){
  u32 r;
  asm("v_cvt_pk_bf16_f32 %0, %1, %2" : "=v"(r) : "v"(lo), "v"(hi));
  return r;
}

// exact-grade gelu: erf via Abramowitz-Stegun 7.1.26 (|eps|<=1.5e-7)
__device__ __forceinline__ float gelu_f(float x){
  float y = fabsf(x) * 0.70710678118654752f;
  float t = __builtin_amdgcn_rcpf(1.f + 0.3275911f*y);
  float p = ((((1.061405429f*t - 1.453152027f)*t + 1.421413741f)*t - 0.284496736f)*t + 0.254829592f)*t;
  float er = 1.f - p*__expf(-y*y);
  er = copysignf(er, x);
  return 0.5f*x*(1.f + er);
}

// window-order row (wi*49+n) -> natural token row (b*3136 + h*56 + w), shift=+3
__device__ __forceinline__ int win_to_src(int orow){
  int wi = orow / 49;
  int n  = orow - wi*49;
  int b  = wi >> 6;
  int wq = wi & 63;
  int wh = wq >> 3, ww = wq & 7;
  int r = n / 7, c = n - r*7;
  int hh = wh*7 + r + 3; if (hh >= 56) hh -= 56;
  int wp = ww*7 + c + 3; if (wp >= 56) wp -= 56;
  return (b*56 + hh)*56 + wp;
}

__global__ void sentinel_kernel(float* o){ o[0] = 1.0e9f; }

// (K,N) f32 -> (N,K) bf16; rows n < scale_lim get *scale (q-scale folding)
__global__ void transpose_cast(const float* __restrict__ in, u16* __restrict__ out,
                               int K, int N, float scale, int scale_lim){
  __shared__ float tile[16][17];
  int kb = blockIdx.x*16, nb = blockIdx.y*16;
  int tx = threadIdx.x, ty = threadIdx.y;
  int k = kb + ty, n = nb + tx;
  tile[ty][tx] = (k < K && n < N) ? in[(size_t)k*N + n] : 0.f;
  __syncthreads();
  int on = nb + ty, ok = kb + tx;
  if (on < N && ok < K){
    float v = tile[tx][ty];
    if (on < scale_lim) v *= scale;
    out[(size_t)on*K + ok] = f2bf(v);
  }
}

// prescale first `lim` entries of bias by s
__global__ void scale_bias(const float* __restrict__ in, float* __restrict__ out,
                           int n, float s, int lim){
  int i = blockIdx.x*256 + threadIdx.x;
  if (i < n) out[i] = in[i] * (i < lim ? s : 1.f);
}

// biasmask[wq][h][m][n], 64x12x64x64 BF16. m=query, n=key. -1e9 on pads.
__global__ void build_biasmask(const float* __restrict__ table, u16* __restrict__ bm){
  int wq = blockIdx.x, h = blockIdx.y;
  int wh = wq >> 3, ww = wq & 7;
  u16* o = bm + (size_t)(wq*12 + h) * 4096;
  for (int i = threadIdx.x; i < 4096; i += 256){
    int m = i >> 6, n = i & 63;
    float v;
    if (m < 49 && n < 49){
      int rm = m/7, cm = m - rm*7;
      int rn = n/7, cn = n - rn*7;
      int idx = (rm - rn + 6)*13 + (cm - cn + 6);
      v = table[idx*12 + h];
      int ym = wh*7 + rm, xm = ww*7 + cm;
      int yn = wh*7 + rn, xn = ww*7 + cn;
      int lm = (ym < 49 ? 0 : (ym < 53 ? 1 : 2))*3 + (xm < 49 ? 0 : (xm < 53 ? 1 : 2));
      int ln = (yn < 49 ? 0 : (yn < 53 ? 1 : 2))*3 + (xn < 49 ? 0 : (xn < 53 ? 1 : 2));
      if (lm != ln) v += -100.f;
    } else {
      v = -1e9f;
    }
    o[i] = f2bf(v);
  }
}

// LayerNorm over C=384, one wave per row. GATHER: row gathered via win_to_src.
template<bool GATHER>
__global__ __launch_bounds__(256) void ln_kernel(const float* __restrict__ x,
    const float* __restrict__ g, const float* __restrict__ b,
    u16* __restrict__ y, int nrows)
{
  int row = blockIdx.x*4 + (threadIdx.x >> 6);
  int lane = threadIdx.x & 63;
  if (row >= nrows) return;
  int src = GATHER ? win_to_src(row) : row;
  const float* xr = x + (size_t)src*384;
  float v[6];
  float s = 0.f, s2 = 0.f;
  #pragma unroll
  for (int p = 0; p < 3; p++){
    float2 t = *(const float2*)(xr + p*128 + lane*2);
    v[p*2] = t.x; v[p*2+1] = t.y;
    s += t.x + t.y; s2 += t.x*t.x + t.y*t.y;
  }
  #pragma unroll
  for (int off = 32; off; off >>= 1){
    s  += __shfl_xor(s,  off);
    s2 += __shfl_xor(s2, off);
  }
  float mean = s * (1.f/384.f);
  float var  = s2 * (1.f/384.f) - mean*mean;
  float rs   = rsqrtf(var + 1e-5f);
  u16* yr = y + (size_t)row*384;
  #pragma unroll
  for (int p = 0; p < 3; p++){
    int c = p*128 + lane*2;
    float a0 = (v[p*2]   - mean)*rs*g[c]   + b[c];
    float a1 = (v[p*2+1] - mean)*rs*g[c+1] + b[c+1];
    *(u32*)(yr + c) = pk_bf16(a0, a1);
  }
}

// ===========================================================================
// 256x128 GEMM, BK=32, 3-buffer, ONE barrier per K-step (r13-verified).
// r14: STRENGTH-REDUCED hot loop (attacks VALUBusy 53% >> MfmaUtil 24%):
//  - kt-loop unrolled x3 -> buffer index is COMPILE-TIME (LDS bases fold
//    into offset immediates; no runtime cur*8192 math). Requires nk%3==0
//    (K=384 -> nk=12, K=1536 -> nk=48: both OK).
//  - 6 staging pointers precomputed once, advanced += 32 elems/step
//    (one v_add vs full (m0+row)*K+kt*32+col remat).
//  - 12 ds_read offsets (aoff/boff) precomputed loop-invariant.
// Schedule/hazards identical to r13: step kt = vmcnt(6|0 tail) -> lgkm(0)
// -> barrier -> stage(kt+2 -> buf (kt+2)%3) -> ds_read buf kt%3 -> 32 MFMA.
// T2 swizzle (64B rows, key=(row>>1)&3), XCD swizzle, bn-fastest,
// operand-swapped MFMA, LDS-transpose bf16 epilogue (r11).
// MODE 0: +bias, bf16 (QKV) | 1: +bias+resid scatter f32 (proj)
//      2: +bias+gelu bf16 (fc1) | 3: +bias accumulate f32 (fc2)
// ===========================================================================
template<int MODE>
__global__ __launch_bounds__(256, 2) void gemm_bf16(
    const u16* __restrict__ A, const u16* __restrict__ Bt,
    const float* __restrict__ bias, const float* __restrict__ resid,
    void* __restrict__ outp, int K, int N, int gn)
{
  __shared__ u16 smem[36864];   // A bufs: 3 x 8192 elems @0; B bufs: 3 x 4096 @24576
  const int tid  = threadIdx.x;
  const int lane = tid & 63, wv = tid >> 6;
  const int wm = wv >> 1, wn = wv & 1;
  const int l15 = lane & 15, lhi = lane >> 4;
  const int key = (l15 >> 1) & 3;       // read-side swizzle key ((row>>1)&3)

  int total = gridDim.x;
  int flat  = blockIdx.x;
  int swz   = flat;
  if ((total & 7) == 0){
    int cpx = total >> 3;
    swz = (flat & 7)*cpx + (flat >> 3);
  }
  int bm = swz / gn, bn = swz - bm*gn;
  const size_t m0 = (size_t)bm * 256;
  const int n0 = bn * 128;

  f4 acc[8][4] = {};

  // ---- loop-invariant staging pointers + LDS dest offsets ----
  const int c0 = tid, c1 = 256 + tid, c2 = 512 + tid, c3 = 768 + tid;
  const u16* sA0 = A + (m0 + (size_t)(c0 >> 2))*K + ((c0 & 3) ^ ((c0 >> 3) & 3))*8;
  const u16* sA1 = A + (m0 + (size_t)(c1 >> 2))*K + ((c1 & 3) ^ ((c1 >> 3) & 3))*8;
  const u16* sA2 = A + (m0 + (size_t)(c2 >> 2))*K + ((c2 & 3) ^ ((c2 >> 3) & 3))*8;
  const u16* sA3 = A + (m0 + (size_t)(c3 >> 2))*K + ((c3 & 3) ^ ((c3 >> 3) & 3))*8;
  const u16* sB0 = Bt + ((size_t)n0 + (c0 >> 2))*K + ((c0 & 3) ^ ((c0 >> 3) & 3))*8;
  const u16* sB1 = Bt + ((size_t)n0 + (c1 >> 2))*K + ((c1 & 3) ^ ((c1 >> 3) & 3))*8;
  const int dA0 = (0   + wv*64)*8, dA1 = (256 + wv*64)*8;
  const int dA2 = (512 + wv*64)*8, dA3 = (768 + wv*64)*8;
  const int dB0 = dA0, dB1 = dA1;

  // ---- loop-invariant ds_read offsets ----
  int aoff[8], boff[4];
  #pragma unroll
  for (int mi = 0; mi < 8; mi++)
    aoff[mi] = (wm*128 + mi*16 + l15)*32 + (lhi ^ key)*8;
  #pragma unroll
  for (int ni = 0; ni < 4; ni++)
    boff[ni] = (wn*64 + ni*16 + l15)*32 + (lhi ^ key)*8;

  const int nk = K >> 5;                // 12 or 48; nk % 3 == 0 required

  // prologue: kt=0 -> buf0, kt=1 -> buf1; pointers then at kt=2
  GL16(sA0, &smem[0*8192 + dA0]); GL16(sA1, &smem[0*8192 + dA1]);
  GL16(sA2, &smem[0*8192 + dA2]); GL16(sA3, &smem[0*8192 + dA3]);
  GL16(sB0, &smem[24576 + 0*4096 + dB0]); GL16(sB1, &smem[24576 + 0*4096 + dB1]);
  GL16(sA0+32, &smem[1*8192 + dA0]); GL16(sA1+32, &smem[1*8192 + dA1]);
  GL16(sA2+32, &smem[1*8192 + dA2]); GL16(sA3+32, &smem[1*8192 + dA3]);
  GL16(sB0+32, &smem[24576 + 1*4096 + dB0]); GL16(sB1+32, &smem[24576 + 1*4096 + dB1]);
  sA0 += 64; sA1 += 64; sA2 += 64; sA3 += 64; sB0 += 64; sB1 += 64;

  int kt = 0;
  #define KSTEP(BUF_CUR, BUF_N2)                                               \
  {                                                                            \
    if (kt + 1 < nk) { asm volatile("s_waitcnt vmcnt(6)" ::: "memory"); }      \
    else             { asm volatile("s_waitcnt vmcnt(0)" ::: "memory"); }      \
    asm volatile("s_waitcnt lgkmcnt(0)" ::: "memory");                         \
    __builtin_amdgcn_s_barrier();                                              \
    if (kt + 2 < nk){                                                          \
      GL16(sA0, &smem[(BUF_N2)*8192 + dA0]);                                   \
      GL16(sA1, &smem[(BUF_N2)*8192 + dA1]);                                   \
      GL16(sA2, &smem[(BUF_N2)*8192 + dA2]);                                   \
      GL16(sA3, &smem[(BUF_N2)*8192 + dA3]);                                   \
      GL16(sB0, &smem[24576 + (BUF_N2)*4096 + dB0]);                           \
      GL16(sB1, &smem[24576 + (BUF_N2)*4096 + dB1]);                           \
      sA0 += 32; sA1 += 32; sA2 += 32; sA3 += 32; sB0 += 32; sB1 += 32;        \
    }                                                                          \
    s8v a[8], bb[4];                                                           \
    _Pragma("unroll")                                                          \
    for (int mi = 0; mi < 8; mi++)                                             \
      a[mi] = *(const s8v*)&smem[(BUF_CUR)*8192 + aoff[mi]];                   \
    _Pragma("unroll")                                                          \
    for (int ni = 0; ni < 4; ni++)                                             \
      bb[ni] = *(const s8v*)&smem[24576 + (BUF_CUR)*4096 + boff[ni]];          \
    _Pragma("unroll")                                                          \
    for (int mi = 0; mi < 8; mi++)                                             \
      _Pragma("unroll")                                                        \
      for (int ni = 0; ni < 4; ni++)                                           \
        acc[mi][ni] = __builtin_amdgcn_mfma_f32_16x16x32_bf16(                 \
            bb[ni], a[mi], acc[mi][ni], 0, 0, 0);                              \
    kt++;                                                                      \
  }

  const int nIter = nk / 3;
  for (int it3 = 0; it3 < nIter; it3++){
    KSTEP(0, 2)
    KSTEP(1, 0)
    KSTEP(2, 1)
  }
  #undef KSTEP

  if constexpr (MODE == 0 || MODE == 2){
    // LDS-transpose epilogue: pack bf16 tile, then wide coalesced stores.
    // tile (256x136 = 69.6KB) overlaps live buffers -> barrier first.
    asm volatile("s_waitcnt lgkmcnt(0)" ::: "memory");
    __builtin_amdgcn_s_barrier();
    u16* tile = smem;
    #pragma unroll
    for (int mi = 0; mi < 8; mi++){
      int ml = wm*128 + mi*16 + l15;
      #pragma unroll
      for (int ni = 0; ni < 4; ni++){
        int nl = wn*64 + ni*16 + lhi*4;
        f4 v = acc[mi][ni];
        float4 b4 = *(const float4*)(bias + n0 + nl);
        v[0] += b4.x; v[1] += b4.y; v[2] += b4.z; v[3] += b4.w;
        u32 p0, p1;
        if constexpr (MODE == 2){
          p0 = pk_bf16(gelu_f(v[0]), gelu_f(v[1]));
          p1 = pk_bf16(gelu_f(v[2]), gelu_f(v[3]));
        } else {
          p0 = pk_bf16(v[0], v[1]);
          p1 = pk_bf16(v[2], v[3]);
        }
        *(u32*)&tile[ml*136 + nl]     = p0;
        *(u32*)&tile[ml*136 + nl + 2] = p1;
      }
    }
    __syncthreads();
    int rr = tid >> 4;            // 0..15
    int cc = (tid & 15) * 8;      // elem col 0..120
    #pragma unroll
    for (int pass = 0; pass < 16; pass++){
      int row = rr + pass*16;
      uint4 val = *(const uint4*)&tile[row*136 + cc];
      *(uint4*)((u16*)outp + ((size_t)((int)m0 + row))*N + n0 + cc) = val;
    }
  } else {
    // f32 modes: float4/lane stores already full-sector.
    #pragma unroll
    for (int mi = 0; mi < 8; mi++){
      int m = (int)m0 + wm*128 + mi*16 + l15;
      int src = 0;
      if constexpr (MODE == 1) src = win_to_src(m);
      #pragma unroll
      for (int ni = 0; ni < 4; ni++){
        int n = n0 + wn*64 + ni*16 + lhi*4;
        f4 v = acc[mi][ni];
        float4 b4 = *(const float4*)(bias + n);
        v[0] += b4.x; v[1] += b4.y; v[2] += b4.z; v[3] += b4.w;
        if constexpr (MODE == 1){
          const float4 r4 = *(const float4*)(resid + (size_t)src*384 + n);
          float4 o4; o4.x = v[0]+r4.x; o4.y = v[1]+r4.y; o4.z = v[2]+r4.z; o4.w = v[3]+r4.w;
          *(float4*)((float*)outp + (size_t)src*384 + n) = o4;
        } else {
          float4* o = (float4*)((float*)outp + (size_t)m*N + n);
          float4 c4 = *o;
          c4.x += v[0]; c4.y += v[1]; c4.z += v[2]; c4.w += v[3];
          *o = c4;
        }
      }
    }
  }
}

// one wave per (window, head): S=QK^T (pad 49->64), +bias+mask, softmax, O=PV
// bm is bf16 (halves bias-read bytes); V loaded via b128.
__global__ __launch_bounds__(256) void attn_kernel(
    const u16* __restrict__ qkv, const u16* __restrict__ bm, u16* __restrict__ ao)
{
  const int wi = blockIdx.x;            // 0..2047
  const int hg = blockIdx.y;            // 0..2
  const int wv = threadIdx.x >> 6, lane = threadIdx.x & 63;
  const int h = hg*4 + wv;
  const int l15 = lane & 15, lhi = lane >> 4;
  const int wq = wi & 63;

  __shared__ u16 Plds[4][64*72];
  __shared__ u16 Vlds[4][32*72];

  const size_t base = (size_t)wi * 49 * 1152;
  s8v z8 = (s8v)0;

  // V -> LDS transposed: Vlds[d][n]; b128 global loads (4/lane)
  #pragma unroll
  for (int i = 0; i < 4; i++){
    int n  = i*16 + (lane >> 2);
    int d8 = (lane & 3)*8;
    s8v v = (n < 49) ? *(const s8v*)&qkv[base + (size_t)n*1152 + 768 + h*32 + d8] : z8;
    #pragma unroll
    for (int j = 0; j < 8; j++)
      Vlds[wv][(d8 + j)*72 + n] = (u16)v[j];
  }

  // Q,K fragments (hd=32 == one MFMA K-step)
  s8v aQ[4], bK[4];
  #pragma unroll
  for (int mi = 0; mi < 4; mi++){
    int rowq = mi*16 + l15;
    aQ[mi] = (rowq < 49) ? *(const s8v*)&qkv[base + (size_t)rowq*1152 +   0 + h*32 + lhi*8] : z8;
    bK[mi] = (rowq < 49) ? *(const s8v*)&qkv[base + (size_t)rowq*1152 + 384 + h*32 + lhi*8] : z8;
  }
  f4 zf = {0.f, 0.f, 0.f, 0.f};
  f4 s[4][4];
  #pragma unroll
  for (int mi = 0; mi < 4; mi++)
    #pragma unroll
    for (int ni = 0; ni < 4; ni++)
      s[mi][ni] = __builtin_amdgcn_mfma_f32_16x16x32_bf16(aQ[mi], bK[ni], zf, 0, 0, 0);

  // + rel-pos bias + shift mask (precomputed bf16, pads = -1e9)
  const u16* bmp = bm + (size_t)(wq*12 + h) * 4096;
  #pragma unroll
  for (int mi = 0; mi < 4; mi++)
    #pragma unroll
    for (int ni = 0; ni < 4; ni++)
      #pragma unroll
      for (int r = 0; r < 4; r++){
        int m = mi*16 + lhi*4 + r, n = ni*16 + l15;
        s[mi][ni][r] += bf2f(bmp[m*64 + n]);
      }

  // softmax over n: 4 in-register + 16-lane shfl_xor reduce
  #pragma unroll
  for (int mi = 0; mi < 4; mi++){
    #pragma unroll
    for (int r = 0; r < 4; r++){
      float mx = fmaxf(fmaxf(s[mi][0][r], s[mi][1][r]), fmaxf(s[mi][2][r], s[mi][3][r]));
      mx = fmaxf(mx, __shfl_xor(mx, 1));
      mx = fmaxf(mx, __shfl_xor(mx, 2));
      mx = fmaxf(mx, __shfl_xor(mx, 4));
      mx = fmaxf(mx, __shfl_xor(mx, 8));
      float sum = 0.f;
      #pragma unroll
      for (int ni = 0; ni < 4; ni++){
        float p = __expf(s[mi][ni][r] - mx);
        s[mi][ni][r] = p; sum += p;
      }
      sum += __shfl_xor(sum, 1);
      sum += __shfl_xor(sum, 2);
      sum += __shfl_xor(sum, 4);
      sum += __shfl_xor(sum, 8);
      float inv = 1.f / sum;
      #pragma unroll
      for (int ni = 0; ni < 4; ni++) s[mi][ni][r] *= inv;
    }
  }

  // P -> LDS (C-layout scatter, bf16)
  #pragma unroll
  for (int mi = 0; mi < 4; mi++)
    #pragma unroll
    for (int ni = 0; ni < 4; ni++)
      #pragma unroll
      for (int r = 0; r < 4; r++){
        int m = mi*16 + lhi*4 + r, n = ni*16 + l15;
        Plds[wv][m*72 + n] = f2bf(s[mi][ni][r]);
      }
  __syncthreads();

  // O = P @ V  (K=64 -> 2 k-steps)
  f4 o[4][2] = {};
  #pragma unroll
  for (int ks = 0; ks < 2; ks++){
    s8v aP[4], bV[2];
    #pragma unroll
    for (int mi = 0; mi < 4; mi++)
      aP[mi] = *(const s8v*)&Plds[wv][(mi*16 + l15)*72 + ks*32 + lhi*8];
    #pragma unroll
    for (int di = 0; di < 2; di++)
      bV[di] = *(const s8v*)&Vlds[wv][(di*16 + l15)*72 + ks*32 + lhi*8];
    #pragma unroll
    for (int mi = 0; mi < 4; mi++)
      #pragma unroll
      for (int di = 0; di < 2; di++)
        o[mi][di] = __builtin_amdgcn_mfma_f32_16x16x32_bf16(aP[mi], bV[di], o[mi][di], 0, 0, 0);
  }

  // store O rows < 49
  #pragma unroll
  for (int mi = 0; mi < 4; mi++)
    #pragma unroll
    for (int di = 0; di < 2; di++)
      #pragma unroll
      for (int r = 0; r < 4; r++){
        int m = mi*16 + lhi*4 + r;
        if (m < 49){
          int d = di*16 + l15;
          ao[((size_t)wi*49 + m)*384 + h*32 + d] = f2bf(o[mi][di][r]);
        }
      }
}

extern "C" void kernel_launch(void* const* d_in, const int* in_sizes, int n_in,
                              void* d_out, int out_size, void* d_ws, size_t ws_size,
                              hipStream_t stream)
{
  const float* x      = (const float*)d_in[0];
  const float* table  = (const float*)d_in[1];
  const float* qkv_w  = (const float*)d_in[2];
  const float* qkv_b  = (const float*)d_in[3];
  const float* proj_w = (const float*)d_in[4];
  const float* proj_b = (const float*)d_in[5];
  const float* n1w    = (const float*)d_in[6];
  const float* n1b    = (const float*)d_in[7];
  const float* n2w    = (const float*)d_in[8];
  const float* n2b    = (const float*)d_in[9];
  const float* w1     = (const float*)d_in[10];
  const float* b1     = (const float*)d_in[11];
  const float* w2     = (const float*)d_in[12];
  const float* b2     = (const float*)d_in[13];
  float* out = (float*)d_out;

  const size_t M = 100352;  // 32 * 3136 tokens (= 2048 windows * 49)
  const float SC = 0.17677669529663689f;  // hd^-0.5

  const size_t R1 = M * 1536 * 2;              // qkv (uses 1152 cols) | mlp hidden
  const size_t R2 = M * 384 * 2;               // ybf | ao | y2
  const size_t R3 = (size_t)64*12*64*64*2;     // biasmask (bf16)
  const size_t WT = (size_t)(1152*384 + 384*384 + 1536*384 + 384*1536) * 2;
  const size_t BB = 1152 * 4;                  // prescaled qkv bias
  const size_t needed = R1 + R2 + R3 + WT + BB;
  if (ws_size < needed){
    sentinel_kernel<<<1, 1, 0, stream>>>(out);
    return;
  }

  char* p = (char*)d_ws;
  u16*   qkvbuf = (u16*)p;                       // R1 (also mlp hidden)
  u16*   ybuf   = (u16*)(p + R1);                // R2 (ybf -> ao -> y2)
  u16*   bmbuf  = (u16*)(p + R1 + R2);           // R3
  u16*   qkvT   = (u16*)(p + R1 + R2 + R3);
  u16*   projT  = qkvT  + (size_t)1152*384;
  u16*   w1T    = projT + (size_t)384*384;
  u16*   w2T    = w1T   + (size_t)1536*384;
  float* qkvb_s = (float*)(p + R1 + R2 + R3 + WT);

  // weight transposes (K,N)->(N,K) bf16; q-scale folded into qkv rows < 384
  transpose_cast<<<dim3(24, 72),  dim3(16,16), 0, stream>>>(qkv_w,  qkvT, 384, 1152, SC, 384);
  transpose_cast<<<dim3(24, 24),  dim3(16,16), 0, stream>>>(proj_w, projT, 384, 384, 1.f, 0);
  transpose_cast<<<dim3(24, 96),  dim3(16,16), 0, stream>>>(w1,     w1T,  384, 1536, 1.f, 0);
  transpose_cast<<<dim3(96, 24),  dim3(16,16), 0, stream>>>(w2,     w2T,  1536, 384, 1.f, 0);
  scale_bias<<<5, 256, 0, stream>>>(qkv_b, qkvb_s, 1152, SC, 384);
  build_biasmask<<<dim3(64, 12), 256, 0, stream>>>(table, bmbuf);

  // LN1 with shift+window gather -> ybf (window-ordered rows)
  ln_kernel<true><<<M/4, 256, 0, stream>>>(x, n1w, n1b, ybuf, (int)M);

  // QKV GEMM: ybf @ qkv_w + b (q prescaled), bf16 out. 256x128 tile, gn=9
  gemm_bf16<0><<<392*9, 256, 0, stream>>>(ybuf, qkvT, qkvb_s, nullptr, qkvbuf, 384, 1152, 9);

  // windowed attention -> ao (overwrites ybf)
  attn_kernel<<<dim3(2048, 3), 256, 0, stream>>>(qkvbuf, bmbuf, ybuf);

  // proj GEMM + un-shift scatter + residual -> out (= x2). gn=3
  gemm_bf16<1><<<392*3, 256, 0, stream>>>(ybuf, projT, proj_b, x, out, 384, 384, 3);

  // LN2 -> y2 (reuses ybuf)
  ln_kernel<false><<<M/4, 256, 0, stream>>>(out, n2w, n2b, ybuf, (int)M);

  // MLP fc1 + gelu -> hidden (reuses qkvbuf region). gn=12
  gemm_bf16<2><<<392*12, 256, 0, stream>>>(ybuf, w1T, b1, nullptr, qkvbuf, 384, 1536, 12);

  // MLP fc2, accumulate into out (x2 + mlp). gn=3
  gemm_bf16<3><<<392*3, 256, 0, stream>>>(qkvbuf, w2T, b2, nullptr, out, 1536, 384, 3);
}

// Round 15
// 885.056 us; speedup vs baseline: 1.1910x; 1.0035x over previous
//
#include <hip/hip_runtime.h>

typedef unsigned short u16;
typedef unsigned int u32;
typedef short s8v __attribute__((ext_vector_type(8)));
typedef float f4 __attribute__((ext_vector_type(4)));

#define GL16(g, l) __builtin_amdgcn_global_load_lds((const __attribute__((address_space(1))) u32*)(g), (__attribute__((address_space(3))) u32*)(l), 16, 0, 0)

__device__ __forceinline__ u16 f2bf(float f){
  u32 u = __builtin_bit_cast(u32, f);
  u32 r = u + 0x7fffu + ((u >> 16) & 1u);
  return (u16)(r >> 16);
}
__device__ __forceinline__ float bf2f(u16 u){
  u32 x = ((u32)u) << 16;
  return __builtin_bit_cast(float, x);
}

// pack 2 f32 -> 2 bf16 (RNE), one instruction
__device__ __forceinline__ u32 pk_bf16(float lo, float hi){
  u32 r;
  asm("v_cvt_pk_bf16_f32 %0, %1, %2" : "=v"(r) : "v"(lo), "v"(hi));
  return r;
}

// exact-grade gelu: erf via Abramowitz-Stegun 7.1.26 (|eps|<=1.5e-7)
__device__ __forceinline__ float gelu_f(float x){
  float y = fabsf(x) * 0.70710678118654752f;
  float t = __builtin_amdgcn_rcpf(1.f + 0.3275911f*y);
  float p = ((((1.061405429f*t - 1.453152027f)*t + 1.421413741f)*t - 0.284496736f)*t + 0.254829592f)*t;
  float er = 1.f - p*__expf(-y*y);
  er = copysignf(er, x);
  return 0.5f*x*(1.f + er);
}

// window-order row (wi*49+n) -> natural token row (b*3136 + h*56 + w), shift=+3
__device__ __forceinline__ int win_to_src(int orow){
  int wi = orow / 49;
  int n  = orow - wi*49;
  int b  = wi >> 6;
  int wq = wi & 63;
  int wh = wq >> 3, ww = wq & 7;
  int r = n / 7, c = n - r*7;
  int hh = wh*7 + r + 3; if (hh >= 56) hh -= 56;
  int wp = ww*7 + c + 3; if (wp >= 56) wp -= 56;
  return (b*56 + hh)*56 + wp;
}

__global__ void sentinel_kernel(float* o){ o[0] = 1.0e9f; }

// (K,N) f32 -> (N,K) bf16; rows n < scale_lim get *scale (q-scale folding)
__global__ void transpose_cast(const float* __restrict__ in, u16* __restrict__ out,
                               int K, int N, float scale, int scale_lim){
  __shared__ float tile[16][17];
  int kb = blockIdx.x*16, nb = blockIdx.y*16;
  int tx = threadIdx.x, ty = threadIdx.y;
  int k = kb + ty, n = nb + tx;
  tile[ty][tx] = (k < K && n < N) ? in[(size_t)k*N + n] : 0.f;
  __syncthreads();
  int on = nb + ty, ok = kb + tx;
  if (on < N && ok < K){
    float v = tile[tx][ty];
    if (on < scale_lim) v *= scale;
    out[(size_t)on*K + ok] = f2bf(v);
  }
}

// prescale first `lim` entries of bias by s
__global__ void scale_bias(const float* __restrict__ in, float* __restrict__ out,
                           int n, float s, int lim){
  int i = blockIdx.x*256 + threadIdx.x;
  if (i < n) out[i] = in[i] * (i < lim ? s : 1.f);
}

// biasmask[wq][h][m][n], 64x12x64x64 BF16. m=query, n=key. -1e9 on pads.
__global__ void build_biasmask(const float* __restrict__ table, u16* __restrict__ bm){
  int wq = blockIdx.x, h = blockIdx.y;
  int wh = wq >> 3, ww = wq & 7;
  u16* o = bm + (size_t)(wq*12 + h) * 4096;
  for (int i = threadIdx.x; i < 4096; i += 256){
    int m = i >> 6, n = i & 63;
    float v;
    if (m < 49 && n < 49){
      int rm = m/7, cm = m - rm*7;
      int rn = n/7, cn = n - rn*7;
      int idx = (rm - rn + 6)*13 + (cm - cn + 6);
      v = table[idx*12 + h];
      int ym = wh*7 + rm, xm = ww*7 + cm;
      int yn = wh*7 + rn, xn = ww*7 + cn;
      int lm = (ym < 49 ? 0 : (ym < 53 ? 1 : 2))*3 + (xm < 49 ? 0 : (xm < 53 ? 1 : 2));
      int ln = (yn < 49 ? 0 : (yn < 53 ? 1 : 2))*3 + (xn < 49 ? 0 : (xn < 53 ? 1 : 2));
      if (lm != ln) v += -100.f;
    } else {
      v = -1e9f;
    }
    o[i] = f2bf(v);
  }
}

// LayerNorm over C=384, one wave per row. GATHER: row gathered via win_to_src.
template<bool GATHER>
__global__ __launch_bounds__(256) void ln_kernel(const float* __restrict__ x,
    const float* __restrict__ g, const float* __restrict__ b,
    u16* __restrict__ y, int nrows)
{
  int row = blockIdx.x*4 + (threadIdx.x >> 6);
  int lane = threadIdx.x & 63;
  if (row >= nrows) return;
  int src = GATHER ? win_to_src(row) : row;
  const float* xr = x + (size_t)src*384;
  float v[6];
  float s = 0.f, s2 = 0.f;
  #pragma unroll
  for (int p = 0; p < 3; p++){
    float2 t = *(const float2*)(xr + p*128 + lane*2);
    v[p*2] = t.x; v[p*2+1] = t.y;
    s += t.x + t.y; s2 += t.x*t.x + t.y*t.y;
  }
  #pragma unroll
  for (int off = 32; off; off >>= 1){
    s  += __shfl_xor(s,  off);
    s2 += __shfl_xor(s2, off);
  }
  float mean = s * (1.f/384.f);
  float var  = s2 * (1.f/384.f) - mean*mean;
  float rs   = rsqrtf(var + 1e-5f);
  u16* yr = y + (size_t)row*384;
  #pragma unroll
  for (int p = 0; p < 3; p++){
    int c = p*128 + lane*2;
    float a0 = (v[p*2]   - mean)*rs*g[c]   + b[c];
    float a1 = (v[p*2+1] - mean)*rs*g[c+1] + b[c+1];
    *(u32*)(yr + c) = pk_bf16(a0, a1);
  }
}

// ===========================================================================
// 256x128 GEMM, BK=32, 3-buffer, ONE barrier per K-step (r13-verified),
// strength-reduced addressing (r14).
// r15: T5 s_setprio(1) around the 32-MFMA cluster. Mechanism: 2 blocks/CU
// at independent phases; setprio lets MFMA-issuing waves win CU arbitration
// over staging/addr waves (m218b/m224: +21-39% when phases are role-split;
// m190 null only for lockstep single-phase).
// MODE 0: +bias, bf16 (QKV) | 1: +bias+resid scatter f32 (proj)
//      2: +bias+gelu bf16 (fc1) | 3: +bias accumulate f32 (fc2)
// ===========================================================================
template<int MODE>
__global__ __launch_bounds__(256, 2) void gemm_bf16(
    const u16* __restrict__ A, const u16* __restrict__ Bt,
    const float* __restrict__ bias, const float* __restrict__ resid,
    void* __restrict__ outp, int K, int N, int gn)
{
  __shared__ u16 smem[36864];   // A bufs: 3 x 8192 elems @0; B bufs: 3 x 4096 @24576
  const int tid  = threadIdx.x;
  const int lane = tid & 63, wv = tid >> 6;
  const int wm = wv >> 1, wn = wv & 1;
  const int l15 = lane & 15, lhi = lane >> 4;
  const int key = (l15 >> 1) & 3;       // read-side swizzle key ((row>>1)&3)

  int total = gridDim.x;
  int flat  = blockIdx.x;
  int swz   = flat;
  if ((total & 7) == 0){
    int cpx = total >> 3;
    swz = (flat & 7)*cpx + (flat >> 3);
  }
  int bm = swz / gn, bn = swz - bm*gn;
  const size_t m0 = (size_t)bm * 256;
  const int n0 = bn * 128;

  f4 acc[8][4] = {};

  // ---- loop-invariant staging pointers + LDS dest offsets ----
  const int c0 = tid, c1 = 256 + tid, c2 = 512 + tid, c3 = 768 + tid;
  const u16* sA0 = A + (m0 + (size_t)(c0 >> 2))*K + ((c0 & 3) ^ ((c0 >> 3) & 3))*8;
  const u16* sA1 = A + (m0 + (size_t)(c1 >> 2))*K + ((c1 & 3) ^ ((c1 >> 3) & 3))*8;
  const u16* sA2 = A + (m0 + (size_t)(c2 >> 2))*K + ((c2 & 3) ^ ((c2 >> 3) & 3))*8;
  const u16* sA3 = A + (m0 + (size_t)(c3 >> 2))*K + ((c3 & 3) ^ ((c3 >> 3) & 3))*8;
  const u16* sB0 = Bt + ((size_t)n0 + (c0 >> 2))*K + ((c0 & 3) ^ ((c0 >> 3) & 3))*8;
  const u16* sB1 = Bt + ((size_t)n0 + (c1 >> 2))*K + ((c1 & 3) ^ ((c1 >> 3) & 3))*8;
  const int dA0 = (0   + wv*64)*8, dA1 = (256 + wv*64)*8;
  const int dA2 = (512 + wv*64)*8, dA3 = (768 + wv*64)*8;
  const int dB0 = dA0, dB1 = dA1;

  // ---- loop-invariant ds_read offsets ----
  int aoff[8], boff[4];
  #pragma unroll
  for (int mi = 0; mi < 8; mi++)
    aoff[mi] = (wm*128 + mi*16 + l15)*32 + (lhi ^ key)*8;
  #pragma unroll
  for (int ni = 0; ni < 4; ni++)
    boff[ni] = (wn*64 + ni*16 + l15)*32 + (lhi ^ key)*8;

  const int nk = K >> 5;                // 12 or 48; nk % 3 == 0 required

  // prologue: kt=0 -> buf0, kt=1 -> buf1; pointers then at kt=2
  GL16(sA0, &smem[0*8192 + dA0]); GL16(sA1, &smem[0*8192 + dA1]);
  GL16(sA2, &smem[0*8192 + dA2]); GL16(sA3, &smem[0*8192 + dA3]);
  GL16(sB0, &smem[24576 + 0*4096 + dB0]); GL16(sB1, &smem[24576 + 0*4096 + dB1]);
  GL16(sA0+32, &smem[1*8192 + dA0]); GL16(sA1+32, &smem[1*8192 + dA1]);
  GL16(sA2+32, &smem[1*8192 + dA2]); GL16(sA3+32, &smem[1*8192 + dA3]);
  GL16(sB0+32, &smem[24576 + 1*4096 + dB0]); GL16(sB1+32, &smem[24576 + 1*4096 + dB1]);
  sA0 += 64; sA1 += 64; sA2 += 64; sA3 += 64; sB0 += 64; sB1 += 64;

  int kt = 0;
  #define KSTEP(BUF_CUR, BUF_N2)                                               \
  {                                                                            \
    if (kt + 1 < nk) { asm volatile("s_waitcnt vmcnt(6)" ::: "memory"); }      \
    else             { asm volatile("s_waitcnt vmcnt(0)" ::: "memory"); }      \
    asm volatile("s_waitcnt lgkmcnt(0)" ::: "memory");                         \
    __builtin_amdgcn_s_barrier();                                              \
    if (kt + 2 < nk){                                                          \
      GL16(sA0, &smem[(BUF_N2)*8192 + dA0]);                                   \
      GL16(sA1, &smem[(BUF_N2)*8192 + dA1]);                                   \
      GL16(sA2, &smem[(BUF_N2)*8192 + dA2]);                                   \
      GL16(sA3, &smem[(BUF_N2)*8192 + dA3]);                                   \
      GL16(sB0, &smem[24576 + (BUF_N2)*4096 + dB0]);                           \
      GL16(sB1, &smem[24576 + (BUF_N2)*4096 + dB1]);                           \
      sA0 += 32; sA1 += 32; sA2 += 32; sA3 += 32; sB0 += 32; sB1 += 32;        \
    }                                                                          \
    s8v a[8], bb[4];                                                           \
    _Pragma("unroll")                                                          \
    for (int mi = 0; mi < 8; mi++)                                             \
      a[mi] = *(const s8v*)&smem[(BUF_CUR)*8192 + aoff[mi]];                   \
    _Pragma("unroll")                                                          \
    for (int ni = 0; ni < 4; ni++)                                             \
      bb[ni] = *(const s8v*)&smem[24576 + (BUF_CUR)*4096 + boff[ni]];          \
    __builtin_amdgcn_s_setprio(1);                                             \
    _Pragma("unroll")                                                          \
    for (int mi = 0; mi < 8; mi++)                                             \
      _Pragma("unroll")                                                        \
      for (int ni = 0; ni < 4; ni++)                                           \
        acc[mi][ni] = __builtin_amdgcn_mfma_f32_16x16x32_bf16(                 \
            bb[ni], a[mi], acc[mi][ni], 0, 0, 0);                              \
    __builtin_amdgcn_s_setprio(0);                                             \
    kt++;                                                                      \
  }

  const int nIter = nk / 3;
  for (int it3 = 0; it3 < nIter; it3++){
    KSTEP(0, 2)
    KSTEP(1, 0)
    KSTEP(2, 1)
  }
  #undef KSTEP

  if constexpr (MODE == 0 || MODE == 2){
    // LDS-transpose epilogue: pack bf16 tile, then wide coalesced stores.
    // tile (256x136 = 69.6KB) overlaps live buffers -> barrier first.
    asm volatile("s_waitcnt lgkmcnt(0)" ::: "memory");
    __builtin_amdgcn_s_barrier();
    u16* tile = smem;
    #pragma unroll
    for (int mi = 0; mi < 8; mi++){
      int ml = wm*128 + mi*16 + l15;
      #pragma unroll
      for (int ni = 0; ni < 4; ni++){
        int nl = wn*64 + ni*16 + lhi*4;
        f4 v = acc[mi][ni];
        float4 b4 = *(const float4*)(bias + n0 + nl);
        v[0] += b4.x; v[1] += b4.y; v[2] += b4.z; v[3] += b4.w;
        u32 p0, p1;
        if constexpr (MODE == 2){
          p0 = pk_bf16(gelu_f(v[0]), gelu_f(v[1]));
          p1 = pk_bf16(gelu_f(v[2]), gelu_f(v[3]));
        } else {
          p0 = pk_bf16(v[0], v[1]);
          p1 = pk_bf16(v[2], v[3]);
        }
        *(u32*)&tile[ml*136 + nl]     = p0;
        *(u32*)&tile[ml*136 + nl + 2] = p1;
      }
    }
    __syncthreads();
    int rr = tid >> 4;            // 0..15
    int cc = (tid & 15) * 8;      // elem col 0..120
    #pragma unroll
    for (int pass = 0; pass < 16; pass++){
      int row = rr + pass*16;
      uint4 val = *(const uint4*)&tile[row*136 + cc];
      *(uint4*)((u16*)outp + ((size_t)((int)m0 + row))*N + n0 + cc) = val;
    }
  } else {
    // f32 modes: float4/lane stores already full-sector.
    #pragma unroll
    for (int mi = 0; mi < 8; mi++){
      int m = (int)m0 + wm*128 + mi*16 + l15;
      int src = 0;
      if constexpr (MODE == 1) src = win_to_src(m);
      #pragma unroll
      for (int ni = 0; ni < 4; ni++){
        int n = n0 + wn*64 + ni*16 + lhi*4;
        f4 v = acc[mi][ni];
        float4 b4 = *(const float4*)(bias + n);
        v[0] += b4.x; v[1] += b4.y; v[2] += b4.z; v[3] += b4.w;
        if constexpr (MODE == 1){
          const float4 r4 = *(const float4*)(resid + (size_t)src*384 + n);
          float4 o4; o4.x = v[0]+r4.x; o4.y = v[1]+r4.y; o4.z = v[2]+r4.z; o4.w = v[3]+r4.w;
          *(float4*)((float*)outp + (size_t)src*384 + n) = o4;
        } else {
          float4* o = (float4*)((float*)outp + (size_t)m*N + n);
          float4 c4 = *o;
          c4.x += v[0]; c4.y += v[1]; c4.z += v[2]; c4.w += v[3];
          *o = c4;
        }
      }
    }
  }
}

// one wave per (window, head): S=QK^T (pad 49->64), +bias+mask, softmax, O=PV
// bm is bf16 (halves bias-read bytes); V loaded via b128. T5 setprio on MFMA.
__global__ __launch_bounds__(256) void attn_kernel(
    const u16* __restrict__ qkv, const u16* __restrict__ bm, u16* __restrict__ ao)
{
  const int wi = blockIdx.x;            // 0..2047
  const int hg = blockIdx.y;            // 0..2
  const int wv = threadIdx.x >> 6, lane = threadIdx.x & 63;
  const int h = hg*4 + wv;
  const int l15 = lane & 15, lhi = lane >> 4;
  const int wq = wi & 63;

  __shared__ u16 Plds[4][64*72];
  __shared__ u16 Vlds[4][32*72];

  const size_t base = (size_t)wi * 49 * 1152;
  s8v z8 = (s8v)0;

  // V -> LDS transposed: Vlds[d][n]; b128 global loads (4/lane)
  #pragma unroll
  for (int i = 0; i < 4; i++){
    int n  = i*16 + (lane >> 2);
    int d8 = (lane & 3)*8;
    s8v v = (n < 49) ? *(const s8v*)&qkv[base + (size_t)n*1152 + 768 + h*32 + d8] : z8;
    #pragma unroll
    for (int j = 0; j < 8; j++)
      Vlds[wv][(d8 + j)*72 + n] = (u16)v[j];
  }

  // Q,K fragments (hd=32 == one MFMA K-step)
  s8v aQ[4], bK[4];
  #pragma unroll
  for (int mi = 0; mi < 4; mi++){
    int rowq = mi*16 + l15;
    aQ[mi] = (rowq < 49) ? *(const s8v*)&qkv[base + (size_t)rowq*1152 +   0 + h*32 + lhi*8] : z8;
    bK[mi] = (rowq < 49) ? *(const s8v*)&qkv[base + (size_t)rowq*1152 + 384 + h*32 + lhi*8] : z8;
  }
  f4 zf = {0.f, 0.f, 0.f, 0.f};
  f4 s[4][4];
  __builtin_amdgcn_s_setprio(1);
  #pragma unroll
  for (int mi = 0; mi < 4; mi++)
    #pragma unroll
    for (int ni = 0; ni < 4; ni++)
      s[mi][ni] = __builtin_amdgcn_mfma_f32_16x16x32_bf16(aQ[mi], bK[ni], zf, 0, 0, 0);
  __builtin_amdgcn_s_setprio(0);

  // + rel-pos bias + shift mask (precomputed bf16, pads = -1e9)
  const u16* bmp = bm + (size_t)(wq*12 + h) * 4096;
  #pragma unroll
  for (int mi = 0; mi < 4; mi++)
    #pragma unroll
    for (int ni = 0; ni < 4; ni++)
      #pragma unroll
      for (int r = 0; r < 4; r++){
        int m = mi*16 + lhi*4 + r, n = ni*16 + l15;
        s[mi][ni][r] += bf2f(bmp[m*64 + n]);
      }

  // softmax over n: 4 in-register + 16-lane shfl_xor reduce
  #pragma unroll
  for (int mi = 0; mi < 4; mi++){
    #pragma unroll
    for (int r = 0; r < 4; r++){
      float mx = fmaxf(fmaxf(s[mi][0][r], s[mi][1][r]), fmaxf(s[mi][2][r], s[mi][3][r]));
      mx = fmaxf(mx, __shfl_xor(mx, 1));
      mx = fmaxf(mx, __shfl_xor(mx, 2));
      mx = fmaxf(mx, __shfl_xor(mx, 4));
      mx = fmaxf(mx, __shfl_xor(mx, 8));
      float sum = 0.f;
      #pragma unroll
      for (int ni = 0; ni < 4; ni++){
        float p = __expf(s[mi][ni][r] - mx);
        s[mi][ni][r] = p; sum += p;
      }
      sum += __shfl_xor(sum, 1);
      sum += __shfl_xor(sum, 2);
      sum += __shfl_xor(sum, 4);
      sum += __shfl_xor(sum, 8);
      float inv = 1.f / sum;
      #pragma unroll
      for (int ni = 0; ni < 4; ni++) s[mi][ni][r] *= inv;
    }
  }

  // P -> LDS (C-layout scatter, bf16)
  #pragma unroll
  for (int mi = 0; mi < 4; mi++)
    #pragma unroll
    for (int ni = 0; ni < 4; ni++)
      #pragma unroll
      for (int r = 0; r < 4; r++){
        int m = mi*16 + lhi*4 + r, n = ni*16 + l15;
        Plds[wv][m*72 + n] = f2bf(s[mi][ni][r]);
      }
  __syncthreads();

  // O = P @ V  (K=64 -> 2 k-steps)
  f4 o[4][2] = {};
  #pragma unroll
  for (int ks = 0; ks < 2; ks++){
    s8v aP[4], bV[2];
    #pragma unroll
    for (int mi = 0; mi < 4; mi++)
      aP[mi] = *(const s8v*)&Plds[wv][(mi*16 + l15)*72 + ks*32 + lhi*8];
    #pragma unroll
    for (int di = 0; di < 2; di++)
      bV[di] = *(const s8v*)&Vlds[wv][(di*16 + l15)*72 + ks*32 + lhi*8];
    __builtin_amdgcn_s_setprio(1);
    #pragma unroll
    for (int mi = 0; mi < 4; mi++)
      #pragma unroll
      for (int di = 0; di < 2; di++)
        o[mi][di] = __builtin_amdgcn_mfma_f32_16x16x32_bf16(aP[mi], bV[di], o[mi][di], 0, 0, 0);
    __builtin_amdgcn_s_setprio(0);
  }

  // store O rows < 49
  #pragma unroll
  for (int mi = 0; mi < 4; mi++)
    #pragma unroll
    for (int di = 0; di < 2; di++)
      #pragma unroll
      for (int r = 0; r < 4; r++){
        int m = mi*16 + lhi*4 + r;
        if (m < 49){
          int d = di*16 + l15;
          ao[((size_t)wi*49 + m)*384 + h*32 + d] = f2bf(o[mi][di][r]);
        }
      }
}

extern "C" void kernel_launch(void* const* d_in, const int* in_sizes, int n_in,
                              void* d_out, int out_size, void* d_ws, size_t ws_size,
                              hipStream_t stream)
{
  const float* x      = (const float*)d_in[0];
  const float* table  = (const float*)d_in[1];
  const float* qkv_w  = (const float*)d_in[2];
  const float* qkv_b  = (const float*)d_in[3];
  const float* proj_w = (const float*)d_in[4];
  const float* proj_b = (const float*)d_in[5];
  const float* n1w    = (const float*)d_in[6];
  const float* n1b    = (const float*)d_in[7];
  const float* n2w    = (const float*)d_in[8];
  const float* n2b    = (const float*)d_in[9];
  const float* w1     = (const float*)d_in[10];
  const float* b1     = (const float*)d_in[11];
  const float* w2     = (const float*)d_in[12];
  const float* b2     = (const float*)d_in[13];
  float* out = (float*)d_out;

  const size_t M = 100352;  // 32 * 3136 tokens (= 2048 windows * 49)
  const float SC = 0.17677669529663689f;  // hd^-0.5

  const size_t R1 = M * 1536 * 2;              // qkv (uses 1152 cols) | mlp hidden
  const size_t R2 = M * 384 * 2;               // ybf | ao | y2
  const size_t R3 = (size_t)64*12*64*64*2;     // biasmask (bf16)
  const size_t WT = (size_t)(1152*384 + 384*384 + 1536*384 + 384*1536) * 2;
  const size_t BB = 1152 * 4;                  // prescaled qkv bias
  const size_t needed = R1 + R2 + R3 + WT + BB;
  if (ws_size < needed){
    sentinel_kernel<<<1, 1, 0, stream>>>(out);
    return;
  }

  char* p = (char*)d_ws;
  u16*   qkvbuf = (u16*)p;                       // R1 (also mlp hidden)
  u16*   ybuf   = (u16*)(p + R1);                // R2 (ybf -> ao -> y2)
  u16*   bmbuf  = (u16*)(p + R1 + R2);           // R3
  u16*   qkvT   = (u16*)(p + R1 + R2 + R3);
  u16*   projT  = qkvT  + (size_t)1152*384;
  u16*   w1T    = projT + (size_t)384*384;
  u16*   w2T    = w1T   + (size_t)1536*384;
  float* qkvb_s = (float*)(p + R1 + R2 + R3 + WT);

  // weight transposes (K,N)->(N,K) bf16; q-scale folded into qkv rows < 384
  transpose_cast<<<dim3(24, 72),  dim3(16,16), 0, stream>>>(qkv_w,  qkvT, 384, 1152, SC, 384);
  transpose_cast<<<dim3(24, 24),  dim3(16,16), 0, stream>>>(proj_w, projT, 384, 384, 1.f, 0);
  transpose_cast<<<dim3(24, 96),  dim3(16,16), 0, stream>>>(w1,     w1T,  384, 1536, 1.f, 0);
  transpose_cast<<<dim3(96, 24),  dim3(16,16), 0, stream>>>(w2,     w2T,  1536, 384, 1.f, 0);
  scale_bias<<<5, 256, 0, stream>>>(qkv_b, qkvb_s, 1152, SC, 384);
  build_biasmask<<<dim3(64, 12), 256, 0, stream>>>(table, bmbuf);

  // LN1 with shift+window gather -> ybf (window-ordered rows)
  ln_kernel<true><<<M/4, 256, 0, stream>>>(x, n1w, n1b, ybuf, (int)M);

  // QKV GEMM: ybf @ qkv_w + b (q prescaled), bf16 out. 256x128 tile, gn=9
  gemm_bf16<0><<<392*9, 256, 0, stream>>>(ybuf, qkvT, qkvb_s, nullptr, qkvbuf, 384, 1152, 9);

  // windowed attention -> ao (overwrites ybf)
  attn_kernel<<<dim3(2048, 3), 256, 0, stream>>>(qkvbuf, bmbuf, ybuf);

  // proj GEMM + un-shift scatter + residual -> out (= x2). gn=3
  gemm_bf16<1><<<392*3, 256, 0, stream>>>(ybuf, projT, proj_b, x, out, 384, 384, 3);

  // LN2 -> y2 (reuses ybuf)
  ln_kernel<false><<<M/4, 256, 0, stream>>>(out, n2w, n2b, ybuf, (int)M);

  // MLP fc1 + gelu -> hidden (reuses qkvbuf region). gn=12
  gemm_bf16<2><<<392*12, 256, 0, stream>>>(ybuf, w1T, b1, nullptr, qkvbuf, 384, 1536, 12);

  // MLP fc2, accumulate into out (x2 + mlp). gn=3
  gemm_bf16<3><<<392*3, 256, 0, stream>>>(qkvbuf, w2T, b2, nullptr, out, 1536, 384, 3);
}

// Round 16
// 874.264 us; speedup vs baseline: 1.2057x; 1.0123x over previous
//
#include <hip/hip_runtime.h>

typedef unsigned short u16;
typedef unsigned int u32;
typedef short s8v __attribute__((ext_vector_type(8)));
typedef float f4 __attribute__((ext_vector_type(4)));

#define GL16(g, l) __builtin_amdgcn_global_load_lds((const __attribute__((address_space(1))) u32*)(g), (__attribute__((address_space(3))) u32*)(l), 16, 0, 0)

__device__ __forceinline__ u16 f2bf(float f){
  u32 u = __builtin_bit_cast(u32, f);
  u32 r = u + 0x7fffu + ((u >> 16) & 1u);
  return (u16)(r >> 16);
}
__device__ __forceinline__ float bf2f(u16 u){
  u32 x = ((u32)u) << 16;
  return __builtin_bit_cast(float, x);
}

// pack 2 f32 -> 2 bf16 (RNE), one instruction
__device__ __forceinline__ u32 pk_bf16(float lo, float hi){
  u32 r;
  asm("v_cvt_pk_bf16_f32 %0, %1, %2" : "=v"(r) : "v"(lo), "v"(hi));
  return r;
}

// exact-grade gelu: erf via Abramowitz-Stegun 7.1.26 (|eps|<=1.5e-7)
__device__ __forceinline__ float gelu_f(float x){
  float y = fabsf(x) * 0.70710678118654752f;
  float t = __builtin_amdgcn_rcpf(1.f + 0.3275911f*y);
  float p = ((((1.061405429f*t - 1.453152027f)*t + 1.421413741f)*t - 0.284496736f)*t + 0.254829592f)*t;
  float er = 1.f - p*__expf(-y*y);
  er = copysignf(er, x);
  return 0.5f*x*(1.f + er);
}

// window-order row (wi*49+n) -> natural token row (b*3136 + h*56 + w), shift=+3
__device__ __forceinline__ int win_to_src(int orow){
  int wi = orow / 49;
  int n  = orow - wi*49;
  int b  = wi >> 6;
  int wq = wi & 63;
  int wh = wq >> 3, ww = wq & 7;
  int r = n / 7, c = n - r*7;
  int hh = wh*7 + r + 3; if (hh >= 56) hh -= 56;
  int wp = ww*7 + c + 3; if (wp >= 56) wp -= 56;
  return (b*56 + hh)*56 + wp;
}

__global__ void sentinel_kernel(float* o){ o[0] = 1.0e9f; }

// (K,N) f32 -> (N,K) bf16; rows n < scale_lim get *scale (q-scale folding)
__global__ void transpose_cast(const float* __restrict__ in, u16* __restrict__ out,
                               int K, int N, float scale, int scale_lim){
  __shared__ float tile[16][17];
  int kb = blockIdx.x*16, nb = blockIdx.y*16;
  int tx = threadIdx.x, ty = threadIdx.y;
  int k = kb + ty, n = nb + tx;
  tile[ty][tx] = (k < K && n < N) ? in[(size_t)k*N + n] : 0.f;
  __syncthreads();
  int on = nb + ty, ok = kb + tx;
  if (on < N && ok < K){
    float v = tile[tx][ty];
    if (on < scale_lim) v *= scale;
    out[(size_t)on*K + ok] = f2bf(v);
  }
}

// prescale first `lim` entries of bias by s
__global__ void scale_bias(const float* __restrict__ in, float* __restrict__ out,
                           int n, float s, int lim){
  int i = blockIdx.x*256 + threadIdx.x;
  if (i < n) out[i] = in[i] * (i < lim ? s : 1.f);
}

// biasmask[wq][h][m][n], 64x12x64x64 BF16. m=query, n=key. -1e9 on pads.
__global__ void build_biasmask(const float* __restrict__ table, u16* __restrict__ bm){
  int wq = blockIdx.x, h = blockIdx.y;
  int wh = wq >> 3, ww = wq & 7;
  u16* o = bm + (size_t)(wq*12 + h) * 4096;
  for (int i = threadIdx.x; i < 4096; i += 256){
    int m = i >> 6, n = i & 63;
    float v;
    if (m < 49 && n < 49){
      int rm = m/7, cm = m - rm*7;
      int rn = n/7, cn = n - rn*7;
      int idx = (rm - rn + 6)*13 + (cm - cn + 6);
      v = table[idx*12 + h];
      int ym = wh*7 + rm, xm = ww*7 + cm;
      int yn = wh*7 + rn, xn = ww*7 + cn;
      int lm = (ym < 49 ? 0 : (ym < 53 ? 1 : 2))*3 + (xm < 49 ? 0 : (xm < 53 ? 1 : 2));
      int ln = (yn < 49 ? 0 : (yn < 53 ? 1 : 2))*3 + (xn < 49 ? 0 : (xn < 53 ? 1 : 2));
      if (lm != ln) v += -100.f;
    } else {
      v = -1e9f;
    }
    o[i] = f2bf(v);
  }
}

// LayerNorm over C=384, one wave per row. GATHER: row gathered via win_to_src.
template<bool GATHER>
__global__ __launch_bounds__(256) void ln_kernel(const float* __restrict__ x,
    const float* __restrict__ g, const float* __restrict__ b,
    u16* __restrict__ y, int nrows)
{
  int row = blockIdx.x*4 + (threadIdx.x >> 6);
  int lane = threadIdx.x & 63;
  if (row >= nrows) return;
  int src = GATHER ? win_to_src(row) : row;
  const float* xr = x + (size_t)src*384;
  float v[6];
  float s = 0.f, s2 = 0.f;
  #pragma unroll
  for (int p = 0; p < 3; p++){
    float2 t = *(const float2*)(xr + p*128 + lane*2);
    v[p*2] = t.x; v[p*2+1] = t.y;
    s += t.x + t.y; s2 += t.x*t.x + t.y*t.y;
  }
  #pragma unroll
  for (int off = 32; off; off >>= 1){
    s  += __shfl_xor(s,  off);
    s2 += __shfl_xor(s2, off);
  }
  float mean = s * (1.f/384.f);
  float var  = s2 * (1.f/384.f) - mean*mean;
  float rs   = rsqrtf(var + 1e-5f);
  u16* yr = y + (size_t)row*384;
  #pragma unroll
  for (int p = 0; p < 3; p++){
    int c = p*128 + lane*2;
    float a0 = (v[p*2]   - mean)*rs*g[c]   + b[c];
    float a1 = (v[p*2+1] - mean)*rs*g[c+1] + b[c+1];
    *(u32*)(yr + c) = pk_bf16(a0, a1);
  }
}

// ===========================================================================
// 256x128 GEMM, BK=32, 3-buffer, ONE barrier per K-step (r13-verified),
// strength-reduced addressing (r14), setprio (r15).
// r16: 512 THREADS / 8 waves (wave tile 64x64, acc 4x4 = 64 VGPR) at the
// SAME 72KB LDS -> still 2 blocks/CU but 16 waves/CU = 4 waves/SIMD (2x r13).
// Mechanism: occupancy pinned ~21% (2 waves/SIMD) across r6/r12/r13 ->
// latency-bound between lockstep phases; more waves = more latency cover.
// Staging: 3 GL16/thread (2 A + 1 B); vmcnt(3) steady, 0 tail. Hazard proof
// unchanged: lgkm(0)-before-barrier covers reads of the buffer stage(kt+2)
// overwrites. launch_bounds(512,4) caps VGPR at 128.
// MODE 0: +bias, bf16 (QKV) | 1: +bias+resid scatter f32 (proj)
//      2: +bias+gelu bf16 (fc1) | 3: +bias accumulate f32 (fc2)
// ===========================================================================
template<int MODE>
__global__ __launch_bounds__(512, 4) void gemm_bf16(
    const u16* __restrict__ A, const u16* __restrict__ Bt,
    const float* __restrict__ bias, const float* __restrict__ resid,
    void* __restrict__ outp, int K, int N, int gn)
{
  __shared__ u16 smem[36864];   // A bufs: 3 x 8192 elems @0; B bufs: 3 x 4096 @24576
  const int tid  = threadIdx.x;
  const int lane = tid & 63, wv = tid >> 6;      // wv 0..7
  const int wm = wv >> 1, wn = wv & 1;           // 4 M-quadrants x 2 N-halves
  const int l15 = lane & 15, lhi = lane >> 4;
  const int key = (l15 >> 1) & 3;       // read-side swizzle key ((row>>1)&3)

  int total = gridDim.x;
  int flat  = blockIdx.x;
  int swz   = flat;
  if ((total & 7) == 0){
    int cpx = total >> 3;
    swz = (flat & 7)*cpx + (flat >> 3);
  }
  int bm = swz / gn, bn = swz - bm*gn;
  const size_t m0 = (size_t)bm * 256;
  const int n0 = bn * 128;

  f4 acc[4][4] = {};

  // ---- loop-invariant staging pointers + LDS dest offsets ----
  // A tile 256x32 = 1024 xb128 loads (2/thread); B tile 128x32 = 512 (1/thread)
  const int c0 = tid, c1 = 512 + tid;
  const u16* sA0 = A + (m0 + (size_t)(c0 >> 2))*K + ((c0 & 3) ^ ((c0 >> 3) & 3))*8;
  const u16* sA1 = A + (m0 + (size_t)(c1 >> 2))*K + ((c1 & 3) ^ ((c1 >> 3) & 3))*8;
  const u16* sB0 = Bt + ((size_t)n0 + (c0 >> 2))*K + ((c0 & 3) ^ ((c0 >> 3) & 3))*8;
  const int dA0 = (0   + wv*64)*8, dA1 = (512 + wv*64)*8;
  const int dB0 = dA0;

  // ---- loop-invariant ds_read offsets ----
  int aoff[4], boff[4];
  #pragma unroll
  for (int mi = 0; mi < 4; mi++)
    aoff[mi] = (wm*64 + mi*16 + l15)*32 + (lhi ^ key)*8;
  #pragma unroll
  for (int ni = 0; ni < 4; ni++)
    boff[ni] = (wn*64 + ni*16 + l15)*32 + (lhi ^ key)*8;

  const int nk = K >> 5;                // 12 or 48; nk % 3 == 0 required

  // prologue: kt=0 -> buf0, kt=1 -> buf1; pointers then at kt=2
  GL16(sA0, &smem[0*8192 + dA0]); GL16(sA1, &smem[0*8192 + dA1]);
  GL16(sB0, &smem[24576 + 0*4096 + dB0]);
  GL16(sA0+32, &smem[1*8192 + dA0]); GL16(sA1+32, &smem[1*8192 + dA1]);
  GL16(sB0+32, &smem[24576 + 1*4096 + dB0]);
  sA0 += 64; sA1 += 64; sB0 += 64;

  int kt = 0;
  #define KSTEP(BUF_CUR, BUF_N2)                                               \
  {                                                                            \
    if (kt + 1 < nk) { asm volatile("s_waitcnt vmcnt(3)" ::: "memory"); }      \
    else             { asm volatile("s_waitcnt vmcnt(0)" ::: "memory"); }      \
    asm volatile("s_waitcnt lgkmcnt(0)" ::: "memory");                         \
    __builtin_amdgcn_s_barrier();                                              \
    if (kt + 2 < nk){                                                          \
      GL16(sA0, &smem[(BUF_N2)*8192 + dA0]);                                   \
      GL16(sA1, &smem[(BUF_N2)*8192 + dA1]);                                   \
      GL16(sB0, &smem[24576 + (BUF_N2)*4096 + dB0]);                           \
      sA0 += 32; sA1 += 32; sB0 += 32;                                         \
    }                                                                          \
    s8v a[4], bb[4];                                                           \
    _Pragma("unroll")                                                          \
    for (int mi = 0; mi < 4; mi++)                                             \
      a[mi] = *(const s8v*)&smem[(BUF_CUR)*8192 + aoff[mi]];                   \
    _Pragma("unroll")                                                          \
    for (int ni = 0; ni < 4; ni++)                                             \
      bb[ni] = *(const s8v*)&smem[24576 + (BUF_CUR)*4096 + boff[ni]];          \
    __builtin_amdgcn_s_setprio(1);                                             \
    _Pragma("unroll")                                                          \
    for (int mi = 0; mi < 4; mi++)                                             \
      _Pragma("unroll")                                                        \
      for (int ni = 0; ni < 4; ni++)                                           \
        acc[mi][ni] = __builtin_amdgcn_mfma_f32_16x16x32_bf16(                 \
            bb[ni], a[mi], acc[mi][ni], 0, 0, 0);                              \
    __builtin_amdgcn_s_setprio(0);                                             \
    kt++;                                                                      \
  }

  const int nIter = nk / 3;
  for (int it3 = 0; it3 < nIter; it3++){
    KSTEP(0, 2)
    KSTEP(1, 0)
    KSTEP(2, 1)
  }
  #undef KSTEP

  if constexpr (MODE == 0 || MODE == 2){
    // LDS-transpose epilogue: pack bf16 tile, then wide coalesced stores.
    // tile (256x136 = 69.6KB) overlaps live buffers -> barrier first.
    asm volatile("s_waitcnt lgkmcnt(0)" ::: "memory");
    __builtin_amdgcn_s_barrier();
    u16* tile = smem;
    #pragma unroll
    for (int mi = 0; mi < 4; mi++){
      int ml = wm*64 + mi*16 + l15;
      #pragma unroll
      for (int ni = 0; ni < 4; ni++){
        int nl = wn*64 + ni*16 + lhi*4;
        f4 v = acc[mi][ni];
        float4 b4 = *(const float4*)(bias + n0 + nl);
        v[0] += b4.x; v[1] += b4.y; v[2] += b4.z; v[3] += b4.w;
        u32 p0, p1;
        if constexpr (MODE == 2){
          p0 = pk_bf16(gelu_f(v[0]), gelu_f(v[1]));
          p1 = pk_bf16(gelu_f(v[2]), gelu_f(v[3]));
        } else {
          p0 = pk_bf16(v[0], v[1]);
          p1 = pk_bf16(v[2], v[3]);
        }
        *(u32*)&tile[ml*136 + nl]     = p0;
        *(u32*)&tile[ml*136 + nl + 2] = p1;
      }
    }
    __syncthreads();
    int rr = tid >> 4;            // 0..31
    int cc = (tid & 15) * 8;      // elem col 0..120
    #pragma unroll
    for (int pass = 0; pass < 8; pass++){
      int row = rr + pass*32;
      uint4 val = *(const uint4*)&tile[row*136 + cc];
      *(uint4*)((u16*)outp + ((size_t)((int)m0 + row))*N + n0 + cc) = val;
    }
  } else {
    // f32 modes: float4/lane stores already full-sector.
    #pragma unroll
    for (int mi = 0; mi < 4; mi++){
      int m = (int)m0 + wm*64 + mi*16 + l15;
      int src = 0;
      if constexpr (MODE == 1) src = win_to_src(m);
      #pragma unroll
      for (int ni = 0; ni < 4; ni++){
        int n = n0 + wn*64 + ni*16 + lhi*4;
        f4 v = acc[mi][ni];
        float4 b4 = *(const float4*)(bias + n);
        v[0] += b4.x; v[1] += b4.y; v[2] += b4.z; v[3] += b4.w;
        if constexpr (MODE == 1){
          const float4 r4 = *(const float4*)(resid + (size_t)src*384 + n);
          float4 o4; o4.x = v[0]+r4.x; o4.y = v[1]+r4.y; o4.z = v[2]+r4.z; o4.w = v[3]+r4.w;
          *(float4*)((float*)outp + (size_t)src*384 + n) = o4;
        } else {
          float4* o = (float4*)((float*)outp + (size_t)m*N + n);
          float4 c4 = *o;
          c4.x += v[0]; c4.y += v[1]; c4.z += v[2]; c4.w += v[3];
          *o = c4;
        }
      }
    }
  }
}

// one wave per (window, head): S=QK^T (pad 49->64), +bias+mask, softmax, O=PV
// bm is bf16 (halves bias-read bytes); V loaded via b128. T5 setprio on MFMA.
__global__ __launch_bounds__(256) void attn_kernel(
    const u16* __restrict__ qkv, const u16* __restrict__ bm, u16* __restrict__ ao)
{
  const int wi = blockIdx.x;            // 0..2047
  const int hg = blockIdx.y;            // 0..2
  const int wv = threadIdx.x >> 6, lane = threadIdx.x & 63;
  const int h = hg*4 + wv;
  const int l15 = lane & 15, lhi = lane >> 4;
  const int wq = wi & 63;

  __shared__ u16 Plds[4][64*72];
  __shared__ u16 Vlds[4][32*72];

  const size_t base = (size_t)wi * 49 * 1152;
  s8v z8 = (s8v)0;

  // V -> LDS transposed: Vlds[d][n]; b128 global loads (4/lane)
  #pragma unroll
  for (int i = 0; i < 4; i++){
    int n  = i*16 + (lane >> 2);
    int d8 = (lane & 3)*8;
    s8v v = (n < 49) ? *(const s8v*)&qkv[base + (size_t)n*1152 + 768 + h*32 + d8] : z8;
    #pragma unroll
    for (int j = 0; j < 8; j++)
      Vlds[wv][(d8 + j)*72 + n] = (u16)v[j];
  }

  // Q,K fragments (hd=32 == one MFMA K-step)
  s8v aQ[4], bK[4];
  #pragma unroll
  for (int mi = 0; mi < 4; mi++){
    int rowq = mi*16 + l15;
    aQ[mi] = (rowq < 49) ? *(const s8v*)&qkv[base + (size_t)rowq*1152 +   0 + h*32 + lhi*8] : z8;
    bK[mi] = (rowq < 49) ? *(const s8v*)&qkv[base + (size_t)rowq*1152 + 384 + h*32 + lhi*8] : z8;
  }
  f4 zf = {0.f, 0.f, 0.f, 0.f};
  f4 s[4][4];
  __builtin_amdgcn_s_setprio(1);
  #pragma unroll
  for (int mi = 0; mi < 4; mi++)
    #pragma unroll
    for (int ni = 0; ni < 4; ni++)
      s[mi][ni] = __builtin_amdgcn_mfma_f32_16x16x32_bf16(aQ[mi], bK[ni], zf, 0, 0, 0);
  __builtin_amdgcn_s_setprio(0);

  // + rel-pos bias + shift mask (precomputed bf16, pads = -1e9)
  const u16* bmp = bm + (size_t)(wq*12 + h) * 4096;
  #pragma unroll
  for (int mi = 0; mi < 4; mi++)
    #pragma unroll
    for (int ni = 0; ni < 4; ni++)
      #pragma unroll
      for (int r = 0; r < 4; r++){
        int m = mi*16 + lhi*4 + r, n = ni*16 + l15;
        s[mi][ni][r] += bf2f(bmp[m*64 + n]);
      }

  // softmax over n: 4 in-register + 16-lane shfl_xor reduce
  #pragma unroll
  for (int mi = 0; mi < 4; mi++){
    #pragma unroll
    for (int r = 0; r < 4; r++){
      float mx = fmaxf(fmaxf(s[mi][0][r], s[mi][1][r]), fmaxf(s[mi][2][r], s[mi][3][r]));
      mx = fmaxf(mx, __shfl_xor(mx, 1));
      mx = fmaxf(mx, __shfl_xor(mx, 2));
      mx = fmaxf(mx, __shfl_xor(mx, 4));
      mx = fmaxf(mx, __shfl_xor(mx, 8));
      float sum = 0.f;
      #pragma unroll
      for (int ni = 0; ni < 4; ni++){
        float p = __expf(s[mi][ni][r] - mx);
        s[mi][ni][r] = p; sum += p;
      }
      sum += __shfl_xor(sum, 1);
      sum += __shfl_xor(sum, 2);
      sum += __shfl_xor(sum, 4);
      sum += __shfl_xor(sum, 8);
      float inv = 1.f / sum;
      #pragma unroll
      for (int ni = 0; ni < 4; ni++) s[mi][ni][r] *= inv;
    }
  }

  // P -> LDS (C-layout scatter, bf16)
  #pragma unroll
  for (int mi = 0; mi < 4; mi++)
    #pragma unroll
    for (int ni = 0; ni < 4; ni++)
      #pragma unroll
      for (int r = 0; r < 4; r++){
        int m = mi*16 + lhi*4 + r, n = ni*16 + l15;
        Plds[wv][m*72 + n] = f2bf(s[mi][ni][r]);
      }
  __syncthreads();

  // O = P @ V  (K=64 -> 2 k-steps)
  f4 o[4][2] = {};
  #pragma unroll
  for (int ks = 0; ks < 2; ks++){
    s8v aP[4], bV[2];
    #pragma unroll
    for (int mi = 0; mi < 4; mi++)
      aP[mi] = *(const s8v*)&Plds[wv][(mi*16 + l15)*72 + ks*32 + lhi*8];
    #pragma unroll
    for (int di = 0; di < 2; di++)
      bV[di] = *(const s8v*)&Vlds[wv][(di*16 + l15)*72 + ks*32 + lhi*8];
    __builtin_amdgcn_s_setprio(1);
    #pragma unroll
    for (int mi = 0; mi < 4; mi++)
      #pragma unroll
      for (int di = 0; di < 2; di++)
        o[mi][di] = __builtin_amdgcn_mfma_f32_16x16x32_bf16(aP[mi], bV[di], o[mi][di], 0, 0, 0);
    __builtin_amdgcn_s_setprio(0);
  }

  // store O rows < 49
  #pragma unroll
  for (int mi = 0; mi < 4; mi++)
    #pragma unroll
    for (int di = 0; di < 2; di++)
      #pragma unroll
      for (int r = 0; r < 4; r++){
        int m = mi*16 + lhi*4 + r;
        if (m < 49){
          int d = di*16 + l15;
          ao[((size_t)wi*49 + m)*384 + h*32 + d] = f2bf(o[mi][di][r]);
        }
      }
}

extern "C" void kernel_launch(void* const* d_in, const int* in_sizes, int n_in,
                              void* d_out, int out_size, void* d_ws, size_t ws_size,
                              hipStream_t stream)
{
  const float* x      = (const float*)d_in[0];
  const float* table  = (const float*)d_in[1];
  const float* qkv_w  = (const float*)d_in[2];
  const float* qkv_b  = (const float*)d_in[3];
  const float* proj_w = (const float*)d_in[4];
  const float* proj_b = (const float*)d_in[5];
  const float* n1w    = (const float*)d_in[6];
  const float* n1b    = (const float*)d_in[7];
  const float* n2w    = (const float*)d_in[8];
  const float* n2b    = (const float*)d_in[9];
  const float* w1     = (const float*)d_in[10];
  const float* b1     = (const float*)d_in[11];
  const float* w2     = (const float*)d_in[12];
  const float* b2     = (const float*)d_in[13];
  float* out = (float*)d_out;

  const size_t M = 100352;  // 32 * 3136 tokens (= 2048 windows * 49)
  const float SC = 0.17677669529663689f;  // hd^-0.5

  const size_t R1 = M * 1536 * 2;              // qkv (uses 1152 cols) | mlp hidden
  const size_t R2 = M * 384 * 2;               // ybf | ao | y2
  const size_t R3 = (size_t)64*12*64*64*2;     // biasmask (bf16)
  const size_t WT = (size_t)(1152*384 + 384*384 + 1536*384 + 384*1536) * 2;
  const size_t BB = 1152 * 4;                  // prescaled qkv bias
  const size_t needed = R1 + R2 + R3 + WT + BB;
  if (ws_size < needed){
    sentinel_kernel<<<1, 1, 0, stream>>>(out);
    return;
  }

  char* p = (char*)d_ws;
  u16*   qkvbuf = (u16*)p;                       // R1 (also mlp hidden)
  u16*   ybuf   = (u16*)(p + R1);                // R2 (ybf -> ao -> y2)
  u16*   bmbuf  = (u16*)(p + R1 + R2);           // R3
  u16*   qkvT   = (u16*)(p + R1 + R2 + R3);
  u16*   projT  = qkvT  + (size_t)1152*384;
  u16*   w1T    = projT + (size_t)384*384;
  u16*   w2T    = w1T   + (size_t)1536*384;
  float* qkvb_s = (float*)(p + R1 + R2 + R3 + WT);

  // weight transposes (K,N)->(N,K) bf16; q-scale folded into qkv rows < 384
  transpose_cast<<<dim3(24, 72),  dim3(16,16), 0, stream>>>(qkv_w,  qkvT, 384, 1152, SC, 384);
  transpose_cast<<<dim3(24, 24),  dim3(16,16), 0, stream>>>(proj_w, projT, 384, 384, 1.f, 0);
  transpose_cast<<<dim3(24, 96),  dim3(16,16), 0, stream>>>(w1,     w1T,  384, 1536, 1.f, 0);
  transpose_cast<<<dim3(96, 24),  dim3(16,16), 0, stream>>>(w2,     w2T,  1536, 384, 1.f, 0);
  scale_bias<<<5, 256, 0, stream>>>(qkv_b, qkvb_s, 1152, SC, 384);
  build_biasmask<<<dim3(64, 12), 256, 0, stream>>>(table, bmbuf);

  // LN1 with shift+window gather -> ybf (window-ordered rows)
  ln_kernel<true><<<M/4, 256, 0, stream>>>(x, n1w, n1b, ybuf, (int)M);

  // QKV GEMM: ybf @ qkv_w + b (q prescaled), bf16 out. 256x128 tile, gn=9
  gemm_bf16<0><<<392*9, 512, 0, stream>>>(ybuf, qkvT, qkvb_s, nullptr, qkvbuf, 384, 1152, 9);

  // windowed attention -> ao (overwrites ybf)
  attn_kernel<<<dim3(2048, 3), 256, 0, stream>>>(qkvbuf, bmbuf, ybuf);

  // proj GEMM + un-shift scatter + residual -> out (= x2). gn=3
  gemm_bf16<1><<<392*3, 512, 0, stream>>>(ybuf, projT, proj_b, x, out, 384, 384, 3);

  // LN2 -> y2 (reuses ybuf)
  ln_kernel<false><<<M/4, 256, 0, stream>>>(out, n2w, n2b, ybuf, (int)M);

  // MLP fc1 + gelu -> hidden (reuses qkvbuf region). gn=12
  gemm_bf16<2><<<392*12, 512, 0, stream>>>(ybuf, w1T, b1, nullptr, qkvbuf, 384, 1536, 12);

  // MLP fc2, accumulate into out (x2 + mlp). gn=3
  gemm_bf16<3><<<392*3, 512, 0, stream>>>(qkvbuf, w2T, b2, nullptr, out, 1536, 384, 3);
}